// Round 7
// baseline (4669.506 us; speedup 1.0000x reference)
//
#include <hip/hip_runtime.h>
#include <stdint.h>
#include <stddef.h>

// Problem constants: B=32, T=512, FD=256, NH=1024, NC=512, NOUT=8
// Established: device inputs f32; output f32; R4-R14 passed (absmax 3.9e-3).
// R15: halve the sync population. lstm_scan keeps the R9 protocol VERBATIM
//      (tagged u64 h-state, full-load spin = detector+transfer, 2 barriers,
//      LDS stage + gl exchange) but each WG now owns 32 units (16 WGs/dir,
//      was 32). Rationale from R14 counters: per-step 3.37us >> protocol
//      floor (~1.7us store->L3->detect); the gap is max-of-32 producer skew
//      + L3 queuing from 64 WGs' 64KB spin attempts (FETCH_SIZE delta
//      R12 vs R14 proves spin traffic is L2-miss traffic served by L3).
//      Both terms scale with WG count -> halve it. MFMA B-frags shared
//      between the two unit-groups (2 LDS reads feed 4 MFMAs).
//      Also reverted R14's gemm XCD swizzle (suspect in +64us non-scan).

typedef short  short8  __attribute__((ext_vector_type(8)));
typedef short  short4v __attribute__((ext_vector_type(4)));
typedef float  float4v __attribute__((ext_vector_type(4)));
typedef unsigned long long u64;

__device__ inline float b2f(short x){
  union { unsigned u; float f; } v; v.u = ((unsigned)(unsigned short)x) << 16; return v.f;
}
__device__ inline short f2b(float f){
  union { float f; unsigned u; } v; v.f = f;
  unsigned r = (v.u + 0x7fffu + ((v.u >> 16) & 1u)) >> 16;
  return (short)r;
}
__device__ inline float sigm(float x){ return 1.f / (1.f + __expf(-x)); }
__device__ inline float tanh_(float x){ return 2.f / (1.f + __expf(-2.f*x)) - 1.f; }

// ---------------------------------------------------------------------------
// Input dtype detection: true-bf16 normals never have exponent >= 0xC0;
// f32 low half-words are uniform -> ~25% exceed.
// ---------------------------------------------------------------------------
__global__ __launch_bounds__(256) void detect_f32(
    const unsigned short* __restrict__ p, unsigned* __restrict__ flag)
{
  const int tid = threadIdx.x;
  unsigned h = 0;
  for (int i = tid; i < 1024; i += 256){
    const unsigned e = (p[i] >> 7) & 0xFFu;
    if (e >= 0xC0u) ++h;
  }
#pragma unroll
  for (int off=32; off>0; off>>=1) h += __shfl_xor(h, off, 64);
  __shared__ unsigned sh[4];
  if ((tid&63)==0) sh[tid>>6] = h;
  __syncthreads();
  if (tid==0) *flag = (sh[0]+sh[1]+sh[2]+sh[3] >= 8u) ? 1u : 0u;
}

// ---------------------------------------------------------------------------
// Batched bf16 normalization: all 16 tensors in ONE launch. Per-tensor block
// ranges precomputed on host; block -> tensor via 16-entry binary search.
// ---------------------------------------------------------------------------
struct CvtArgs {
  const void* src[16];
  short*      dst[16];
  int         n[16];
  int         boff[17];   // prefix block offsets; boff[16] = total blocks
};

__global__ __launch_bounds__(256) void to_bf16_batch(
    CvtArgs a, const unsigned* __restrict__ flag)
{
  const int b = blockIdx.x;
  int lo = 0, hi = 15;
  while (lo < hi){
    const int mid = (lo + hi + 1) >> 1;
    if (b >= a.boff[mid]) lo = mid; else hi = mid - 1;
  }
  const int i   = lo;
  const int idx = (b - a.boff[i])*256 + (int)threadIdx.x;
  if (idx >= a.n[i]) return;
  if (*flag) a.dst[i][idx] = f2b(((const float*)a.src[i])[idx]);
  else       a.dst[i][idx] = ((const short*)a.src[i])[idx];
}

// ---------------------------------------------------------------------------
// GEMM: C[M,N] = bf16( A[M,K] @ W[N,K]^T + bias1[n] (+ bias2[n]) ).
// 128x128 block tile, BK=32, 4 waves, 16x16x32 bf16 MFMA. All dims multiples.
// ---------------------------------------------------------------------------
__global__ __launch_bounds__(256) void gemm_bt(
    const short* __restrict__ A, const short* __restrict__ W,
    short* __restrict__ C, const short* __restrict__ bias1,
    const short* __restrict__ bias2, int N, int K)
{
  __shared__ __align__(16) short lA[128*40];
  __shared__ __align__(16) short lW[128*40];
  const int tid  = threadIdx.x;
  const int lane = tid & 63, wv = tid >> 6;
  const int wm = wv >> 1, wn = wv & 1;
  const int quad = lane >> 4, l15 = lane & 15;
  const long m0 = (long)blockIdx.y * 128, n0 = (long)blockIdx.x * 128;

  float4v acc[4][4];
#pragma unroll
  for (int i=0;i<4;++i)
#pragma unroll
    for (int j=0;j<4;++j) acc[i][j] = (float4v)0.f;

  const int r  = tid >> 2;
  const int kc = tid & 3;
  const int nkt = K >> 5;
  for (int kt = 0; kt < nkt; ++kt) {
    __syncthreads();
    const short* ga = A + (m0 + r) * (long)K + kt*32 + kc*8;
    const short* gw = W + (n0 + r) * (long)K + kt*32 + kc*8;
    short8 a0 = *(const short8*)ga;
    short8 a1 = *(const short8*)(ga + 64*(long)K);
    short8 w0 = *(const short8*)gw;
    short8 w1 = *(const short8*)(gw + 64*(long)K);
    *(short8*)&lA[r*40 + kc*8]        = a0;
    *(short8*)&lA[(r+64)*40 + kc*8]   = a1;
    *(short8*)&lW[r*40 + kc*8]        = w0;
    *(short8*)&lW[(r+64)*40 + kc*8]   = w1;
    __syncthreads();
    short8 af[4], bfr[4];
#pragma unroll
    for (int i=0;i<4;++i) af[i]  = *(const short8*)&lA[(wm*64 + i*16 + l15)*40 + quad*8];
#pragma unroll
    for (int j=0;j<4;++j) bfr[j] = *(const short8*)&lW[(wn*64 + j*16 + l15)*40 + quad*8];
#pragma unroll
    for (int i=0;i<4;++i)
#pragma unroll
      for (int j=0;j<4;++j)
        acc[i][j] = __builtin_amdgcn_mfma_f32_16x16x32_bf16(af[i], bfr[j], acc[i][j], 0, 0, 0);
  }
#pragma unroll
  for (int j=0;j<4;++j){
    const long n = n0 + wn*64 + j*16 + l15;
    float bs = b2f(bias1[n]);
    if (bias2) bs += b2f(bias2[n]);
#pragma unroll
    for (int i=0;i<4;++i){
      const long mb = m0 + wm*64 + i*16 + quad*4;
#pragma unroll
      for (int g=0; g<4; ++g)
        C[(mb+g)*(long)N + n] = f2b(acc[i][j][g] + bs);
    }
  }
}

// ---------------------------------------------------------------------------
// Row-wise LayerNorm (eps=1e-5) + LeakyReLU(0.01) (+ optional pad-mask zero).
// ---------------------------------------------------------------------------
__global__ __launch_bounds__(256) void ln_lrelu(
    const short* __restrict__ X, const short* __restrict__ g,
    const short* __restrict__ be, short* __restrict__ out,
    const int* __restrict__ lens, const int domask)
{
  const int row = blockIdx.x, tid = threadIdx.x;
  const short* xr = X + (size_t)row * 1024;
  short4v xv = *(const short4v*)(xr + tid*4);
  float v[4];
#pragma unroll
  for (int k=0;k<4;++k) v[k] = b2f(xv[k]);
  float s  = v[0]+v[1]+v[2]+v[3];
  float sq = v[0]*v[0]+v[1]*v[1]+v[2]*v[2]+v[3]*v[3];
#pragma unroll
  for (int off=32; off>0; off>>=1){
    s  += __shfl_xor(s,  off, 64);
    sq += __shfl_xor(sq, off, 64);
  }
  __shared__ float red[8];
  if ((tid&63)==0){ red[tid>>6] = s; red[4+(tid>>6)] = sq; }
  __syncthreads();
  s  = red[0]+red[1]+red[2]+red[3];
  sq = red[4]+red[5]+red[6]+red[7];
  const float mean = s * (1.f/1024.f);
  const float var  = sq * (1.f/1024.f) - mean*mean;
  const float rstd = rsqrtf(var + 1e-5f);
  float zmul = 1.f;
  if (domask){ const int b = row >> 9, t = row & 511; if (t >= lens[b]) zmul = 0.f; }
  short4v o;
#pragma unroll
  for (int k=0;k<4;++k){
    const int n = tid*4 + k;
    float y = (v[k]-mean)*rstd*b2f(g[n]) + b2f(be[n]);
    y = (y >= 0.f) ? y : 0.01f*y;
    o[k] = f2b(y * zmul);
  }
  *(short4v*)(out + (size_t)row*1024 + tid*4) = o;
}

// ---------------------------------------------------------------------------
// Persistent bidirectional LSTM scan — R15: R9 protocol, 32 units per WG.
// Grid = 16*ndir WGs x 256 thr. WG dir = dir0 + (blk>>4); u0 = (blk&15)*32.
// Wave wv computes gate wv (torch i,f,g,o) for both 16-unit groups; the
// h B-fragment is shared: per ks, 2 LDS reads feed 4 MFMAs.
// h state global: [dir][buf(step parity)][32 batch][256 pair] u64,
//   hi 32 = tag (epoch<<10 | producing step+1), lo 32 = packed 2xbf16.
// Aligned 8B stores are single-copy atomic: consumers poll the DATA word
// (tag match == payload in hand; the successful spin attempt IS the
// transfer). Per-instruction coalesced: wave loads 64 consecutive u64.
// Two barriers/step; hsh double-buffered; inductive no-clobber proof as R9.
// ---------------------------------------------------------------------------
__global__ __launch_bounds__(256) void lstm_scan(
    const short* __restrict__ xp, const int xp_cols, const int dir0,
    const short* __restrict__ whh,      // layer base: [2][2048][512]
    u64* __restrict__ hstate,           // [2][2][32][256] tagged u64
    short* __restrict__ hout,           // [32][512][1024]
    const unsigned epoch)
{
  const int wg = blockIdx.x;
  const int dloc = wg >> 4, d = dir0 + dloc;
  const int u0 = (wg & 15) * 32;
  const int tid = threadIdx.x, lane = tid & 63, wv = tid >> 6;
  const int quad = lane >> 4, l15 = lane & 15;

  // A-frags for the two 16-unit groups of this WG (gate wv).
  short8 af0[16], af1[16];
  {
    const short* wr0 = whh + ((size_t)d*2048 + wv*512 + u0 + l15)*512 + quad*8;
    const short* wr1 = wr0 + (size_t)16*512;
#pragma unroll
    for (int ks=0; ks<16; ++ks){
      af0[ks] = *(const short8*)(wr0 + ks*32);
      af1[ks] = *(const short8*)(wr1 + ks*32);
    }
  }

  // gate-math ownership: thread = (batch bb, pairs pp and pp+8 of this WG)
  const int bb = tid >> 3, pp = tid & 7;
  float cst[4] = {0.f, 0.f, 0.f, 0.f};
  __shared__ __align__(16) unsigned hsh[2][32*260];  // double-buffered staging
  __shared__ float gl[4][32][33];
  const unsigned tbase = epoch << 10;

  for (int step=0; step<512; ++step){
    const int t = d ? (511-step) : step;
    // xp prefetch (overlaps the poll): 4 frags (2 unit-groups x 2 batch halves)
    short4v x00, x01, x10, x11;
    {
      const size_t gb = (size_t)dloc*2048 + (size_t)wv*512 + u0 + quad*4;
      const short* pA = xp + ((size_t)l15*512      + t)*xp_cols + gb;
      const short* pB = xp + ((size_t)(l15+16)*512 + t)*xp_cols + gb;
      x00 = *(const short4v*)pA;
      x01 = *(const short4v*)(pA + 16);
      x10 = *(const short4v*)pB;
      x11 = *(const short4v*)(pB + 16);
    }
    // poll + stage: thread owns pair `tid` of every batch k (lane-consecutive
    // global loads AND lane-consecutive LDS writes -> conflict-free).
    unsigned* stg = &hsh[step&1][tid];
    if (step == 0){
#pragma unroll
      for (int k=0;k<32;++k) stg[k*260] = 0u;        // h_0 = 0, no poll
    } else {
      const u64* hq = hstate + ((size_t)(d*2 + (step&1))<<13) + tid;
      const unsigned tgt = tbase + (unsigned)step;
      u64 v[32];
      for(;;){
        unsigned ok = 1u;
#pragma unroll
        for (int k=0;k<32;++k)
          v[k] = __hip_atomic_load(hq + (size_t)k*256,
                                   __ATOMIC_RELAXED, __HIP_MEMORY_SCOPE_AGENT);
#pragma unroll
        for (int k=0;k<32;++k) ok &= (unsigned)((unsigned)(v[k] >> 32) == tgt);
        if (ok) break;
        __builtin_amdgcn_s_sleep(1);
      }
#pragma unroll
      for (int k=0;k<32;++k) stg[k*260] = (unsigned)v[k];
    }
    __syncthreads();   // B1: staged h ready (also fences prev-step gl reads)

    // MFMA: 4 acc chains (unit-group x batch-half); B-frags shared per ks.
    float4v a00, a01, a10, a11;
#pragma unroll
    for (int g=0; g<4; ++g){
      a00[g] = b2f(x00[g]); a01[g] = b2f(x01[g]);
      a10[g] = b2f(x10[g]); a11[g] = b2f(x11[g]);
    }
    const short* hs = (const short*)&hsh[step&1][0];
#pragma unroll
    for (int ks=0; ks<16; ++ks){
      short8 b0 = *(const short8*)(hs + (size_t)l15*520      + ks*32 + quad*8);
      short8 b1 = *(const short8*)(hs + (size_t)(l15+16)*520 + ks*32 + quad*8);
      a00 = __builtin_amdgcn_mfma_f32_16x16x32_bf16(af0[ks], b0, a00, 0, 0, 0);
      a01 = __builtin_amdgcn_mfma_f32_16x16x32_bf16(af1[ks], b0, a01, 0, 0, 0);
      a10 = __builtin_amdgcn_mfma_f32_16x16x32_bf16(af0[ks], b1, a10, 0, 0, 0);
      a11 = __builtin_amdgcn_mfma_f32_16x16x32_bf16(af1[ks], b1, a11, 0, 0, 0);
    }
#pragma unroll
    for (int g=0; g<4; ++g){
      gl[wv][quad*4+g][l15]        = a00[g];   // grp0, batches 0..15
      gl[wv][16+quad*4+g][l15]     = a01[g];   // grp1, batches 0..15
      gl[wv][quad*4+g][l15+16]     = a10[g];   // grp0, batches 16..31
      gl[wv][16+quad*4+g][l15+16]  = a11[g];   // grp1, batches 16..31
    }
    __syncthreads();   // B2: gl ready (also fences prev-gen hsh buffer reads)

    float hv[4];
#pragma unroll
    for (int i=0; i<4; ++i){
      const int uu = ((i >> 1) << 4) | (2*pp + (i & 1));  // 2pp,2pp+1,16+2pp,17+2pp
      const float gi = gl[0][uu][bb], gf = gl[1][uu][bb];
      const float gg = gl[2][uu][bb], go = gl[3][uu][bb];
      const float c = sigm(gf)*cst[i] + sigm(gi)*tanh_(gg);
      cst[i] = c;
      hv[i] = sigm(go) * tanh_(c);
    }
    const unsigned hw0 = (unsigned)(unsigned short)f2b(hv[0])
                       | ((unsigned)(unsigned short)f2b(hv[1]) << 16);
    const unsigned hw1 = (unsigned)(unsigned short)f2b(hv[2])
                       | ((unsigned)(unsigned short)f2b(hv[3]) << 16);
    const u64 tag = (u64)(tbase + (unsigned)step + 1u) << 32;
    u64* hn = hstate + ((size_t)(d*2 + ((step+1)&1))<<13) + (size_t)bb*256 + (u0>>1) + pp;
    __hip_atomic_store(hn,     tag | (u64)hw0,
                       __ATOMIC_RELAXED, __HIP_MEMORY_SCOPE_AGENT);
    __hip_atomic_store(hn + 8, tag | (u64)hw1,
                       __ATOMIC_RELAXED, __HIP_MEMORY_SCOPE_AGENT);
    unsigned* ho = (unsigned*)&hout[((size_t)bb*512 + t)*1024 + d*512 + u0 + 2*pp];
    ho[0] = hw0;
    ho[8] = hw1;   // units +16 -> 8 unsigneds ahead
    // no drain, no flag: the tagged store is self-announcing
  }
}

// ---------------------------------------------------------------------------
// Attention (window_len=1) + classifier. One block per batch element.
// b_u omitted: constant shift cancels in softmax. Output: f32.
// ---------------------------------------------------------------------------
__global__ __launch_bounds__(256) void attn_cls(
    const short* __restrict__ hseq, const short* __restrict__ wu,
    const short* __restrict__ Wc, const short* __restrict__ bc,
    const int* __restrict__ lens, float* __restrict__ out)
{
  const int b = blockIdx.x, tid = threadIdx.x, lane = tid & 63, wv = tid >> 6;
  const int len = lens[b];
  __shared__ float wus[1024];
  __shared__ float sc[512];
  __shared__ float redx[8];
  __shared__ float pooled[1024];
  for (int i=tid; i<1024; i+=256) wus[i] = b2f(wu[i]);
  __syncthreads();
  const short* hb = hseq + (size_t)b*512*1024;
  for (int t=wv; t<512; t+=4){
    const short* hr = hb + (size_t)t*1024;
    float s = 0.f;
#pragma unroll
    for (int j=0;j<16;++j) s += b2f(hr[lane + j*64]) * wus[lane + j*64];
#pragma unroll
    for (int off=32; off>0; off>>=1) s += __shfl_xor(s, off, 64);
    if (lane==0) sc[t] = (t < len) ? s : -3.0e38f;
  }
  __syncthreads();
  float m = -3.0e38f;
  for (int i=tid;i<512;i+=256) m = fmaxf(m, sc[i]);
#pragma unroll
  for (int off=32; off>0; off>>=1) m = fmaxf(m, __shfl_xor(m, off, 64));
  if (lane==0) redx[wv] = m;
  __syncthreads();
  m = fmaxf(fmaxf(redx[0],redx[1]), fmaxf(redx[2],redx[3]));
  float ssum = 0.f;
  for (int i=tid;i<512;i+=256){
    float e = (i<len) ? __expf(sc[i]-m) : 0.f;
    sc[i] = e;
    ssum += e;
  }
#pragma unroll
  for (int off=32; off>0; off>>=1) ssum += __shfl_xor(ssum, off, 64);
  if (lane==0) redx[4+wv] = ssum;
  __syncthreads();
  ssum = redx[4]+redx[5]+redx[6]+redx[7];
  const float inv = 1.f/ssum;
  float4v pa = (float4v)0.f;
  const int k0 = tid*4;
  for (int t=0; t<len; ++t){
    const float a = sc[t];
    short4v hv = *(const short4v*)(hb + (size_t)t*1024 + k0);
    pa[0] += a*b2f(hv[0]); pa[1] += a*b2f(hv[1]);
    pa[2] += a*b2f(hv[2]); pa[3] += a*b2f(hv[3]);
  }
  pooled[k0+0] = pa[0]*inv; pooled[k0+1] = pa[1]*inv;
  pooled[k0+2] = pa[2]*inv; pooled[k0+3] = pa[3]*inv;
  __syncthreads();
  const int j = tid >> 5, l32 = tid & 31;
  float s2 = 0.f;
  for (int kk=l32; kk<1024; kk+=32) s2 += b2f(Wc[j*1024+kk]) * pooled[kk];
#pragma unroll
  for (int off=16; off>0; off>>=1) s2 += __shfl_xor(s2, off, 32);
  if (l32==0) out[b*8+j] = s2 + b2f(bc[j]);
}

// ---------------------------------------------------------------------------
extern "C" void kernel_launch(void* const* d_in, const int* in_sizes, int n_in,
                              void* d_out, int out_size, void* d_ws, size_t ws_size,
                              hipStream_t stream)
{
  (void)in_sizes; (void)n_in; (void)out_size;
  const int*   lens = (const int*)d_in[1];
  float* outp = (float*)d_out;

  const size_t SZ_XP_A = (size_t)16384*4096*2;   // 134,217,728 B
  const size_t SZ_XP_B = (size_t)16384*2048*2;   //  67,108,864 B
  const size_t SZ_H    = (size_t)16384*1024*2;   //  33,554,432 B
  const size_t SZ_HS   = 262144;                 // 4 bufs x 8192 tagged u64
  const size_t SZ_CNT  = 16384;
  const size_t SZ_NORM = 37000000;               // bf16 copies of all inputs
  const bool planA = ws_size >= SZ_XP_A + 2*SZ_H + SZ_HS + SZ_CNT + SZ_NORM;
  const bool planB = !planA && ws_size >= SZ_XP_B + 2*SZ_H + SZ_HS + SZ_CNT + SZ_NORM;
  if (!planA && !planB) return;  // clean failure beats a core dump
  const size_t xpsz = planA ? SZ_XP_A : SZ_XP_B;

  char* ws = (char*)d_ws;
  short*    XP  = (short*)ws;
  short*    HB  = (short*)(ws + xpsz);
  short*    HC  = (short*)(ws + xpsz + SZ_H);
  u64*      HS64= (u64*)(ws + xpsz + 2*SZ_H);
  unsigned* CNT = (unsigned*)(ws + xpsz + 2*SZ_H + SZ_HS);
  unsigned* FLAG = CNT + 4000;
  short*    pool = (short*)(ws + xpsz + 2*SZ_H + SZ_HS + SZ_CNT);

  // carve bf16 copies (128-element aligned)
  size_t off = 0;
  auto carve = [&](size_t n){ short* p = pool + off; off += (n + 127) & ~(size_t)127; return p; };
  short* x   = carve(4194304);
  short* W1  = carve(262144);
  short* b1  = carve(1024);
  short* g1  = carve(1024);
  short* be1 = carve(1024);
  short* W2  = carve(1048576);
  short* b2  = carve(1024);
  short* g2  = carve(1024);
  short* be2 = carve(1024);
  short* wih = carve(8388608);
  short* whh = carve(4194304);
  short* bih = carve(8192);
  short* bhh = carve(8192);
  short* wu  = carve(1024);
  short* Wc  = carve(8192);
  short* bc  = carve(8);

  // zero the tagged h-state once: no garbage tag can match epoch>=1 targets.
  hipMemsetAsync(HS64, 0, SZ_HS, stream);
  detect_f32<<<1, 256, 0, stream>>>((const unsigned short*)d_in[0], FLAG);

  // single batched convert launch for all 16 tensors
  {
    struct { int idx; short* dst; int n; } cv[16] = {
      {0,x,4194304},{2,W1,262144},{3,b1,1024},{4,g1,1024},{5,be1,1024},
      {6,W2,1048576},{7,b2,1024},{8,g2,1024},{9,be2,1024},
      {10,wih,8388608},{11,whh,4194304},{12,bih,8192},{13,bhh,8192},
      {14,wu,1024},{16,Wc,8192},{17,bc,8}
    };
    CvtArgs a;
    int acc = 0;
    for (int i=0;i<16;++i){
      a.src[i]  = d_in[cv[i].idx];
      a.dst[i]  = cv[i].dst;
      a.n[i]    = cv[i].n;
      a.boff[i] = acc;
      acc += (cv[i].n + 255) / 256;
    }
    a.boff[16] = acc;
    to_bf16_batch<<<acc, 256, 0, stream>>>(a, FLAG);
  }

  dim3 blk(256);
  // extract MLP
  gemm_bt<<<dim3(8,128),  blk, 0, stream>>>(x,  W1, XP, b1, nullptr, 1024, 256);
  ln_lrelu<<<16384, blk, 0, stream>>>(XP, g1, be1, HB, lens, 0);
  gemm_bt<<<dim3(8,128),  blk, 0, stream>>>(HB, W2, XP, b2, nullptr, 1024, 1024);
  ln_lrelu<<<16384, blk, 0, stream>>>(XP, g2, be2, HC, lens, 1);   // + pad mask

  const short* lin[2]  = { HC, HB };   // layer inputs
  short*       lout[2] = { HB, HC };   // layer outputs
  for (int l = 0; l < 2; ++l){
    const short* whh_l = whh + (size_t)l*2*2048*512;
    if (planA){
      gemm_bt<<<dim3(32,128), blk, 0, stream>>>(
          lin[l], wih + (size_t)l*4096*1024, XP,
          bih + l*4096, bhh + l*4096, 4096, 1024);
      lstm_scan<<<32, blk, 0, stream>>>(XP, 4096, 0, whh_l, HS64, lout[l],
                                        (unsigned)(l+1));
    } else {
      for (int d = 0; d < 2; ++d){
        gemm_bt<<<dim3(16,128), blk, 0, stream>>>(
            lin[l], wih + ((size_t)(l*2+d))*2048*1024, XP,
            bih + (l*2+d)*2048, bhh + (l*2+d)*2048, 2048, 1024);
        lstm_scan<<<16, blk, 0, stream>>>(XP, 2048, d, whh_l, HS64, lout[l],
                                          (unsigned)(l+1));
      }
    }
  }
  // attention + classifier
  attn_cls<<<32, blk, 0, stream>>>(HC, wu, Wc, bc, lens, outp);
}

// Round 8
// 4200.662 us; speedup vs baseline: 1.1116x; 1.1116x over previous
//
#include <hip/hip_runtime.h>
#include <stdint.h>
#include <stddef.h>

// Problem constants: B=32, T=512, FD=256, NH=1024, NC=512, NOUT=8
// Established: device inputs f32; output f32; R4-R15 passed (absmax 3.9e-3).
// R16: scan frozen at R9-verbatim (6 variants all lost; 1725us/dispatch is
//      the protocol floor). This round attacks the ~740us non-scan tail:
//      gemm_bt staging upgraded to global_load_lds width=16 (m97 recipe:
//      linear LDS [128][32], wave-uniform dest + lane*16) with pre-swizzled
//      global source + XOR-read (chunk ^= row&3, involution, both sides) to
//      cut ds_read_b128 bank conflicts 8-way -> 4-way. Fragment math, tile,
//      epilogue unchanged. No XCD swizzle (R15 proved it hurt).

typedef short  short8  __attribute__((ext_vector_type(8)));
typedef short  short4v __attribute__((ext_vector_type(4)));
typedef float  float4v __attribute__((ext_vector_type(4)));
typedef unsigned long long u64;

__device__ inline float b2f(short x){
  union { unsigned u; float f; } v; v.u = ((unsigned)(unsigned short)x) << 16; return v.f;
}
__device__ inline short f2b(float f){
  union { float f; unsigned u; } v; v.f = f;
  unsigned r = (v.u + 0x7fffu + ((v.u >> 16) & 1u)) >> 16;
  return (short)r;
}
__device__ inline float sigm(float x){ return 1.f / (1.f + __expf(-x)); }
__device__ inline float tanh_(float x){ return 2.f / (1.f + __expf(-2.f*x)) - 1.f; }

// async global->LDS, 16B per lane; LDS dest is wave-uniform base + lane*16.
typedef const __attribute__((address_space(1))) unsigned gu32;
typedef __attribute__((address_space(3))) unsigned lu32;
__device__ inline void gld16(const void* g, void* l){
  __builtin_amdgcn_global_load_lds((gu32*)g, (lu32*)l, 16, 0, 0);
}

// ---------------------------------------------------------------------------
// Input dtype detection: true-bf16 normals never have exponent >= 0xC0;
// f32 low half-words are uniform -> ~25% exceed.
// ---------------------------------------------------------------------------
__global__ __launch_bounds__(256) void detect_f32(
    const unsigned short* __restrict__ p, unsigned* __restrict__ flag)
{
  const int tid = threadIdx.x;
  unsigned h = 0;
  for (int i = tid; i < 1024; i += 256){
    const unsigned e = (p[i] >> 7) & 0xFFu;
    if (e >= 0xC0u) ++h;
  }
#pragma unroll
  for (int off=32; off>0; off>>=1) h += __shfl_xor(h, off, 64);
  __shared__ unsigned sh[4];
  if ((tid&63)==0) sh[tid>>6] = h;
  __syncthreads();
  if (tid==0) *flag = (sh[0]+sh[1]+sh[2]+sh[3] >= 8u) ? 1u : 0u;
}

// ---------------------------------------------------------------------------
// Batched bf16 normalization: all 16 tensors in ONE launch. Per-tensor block
// ranges precomputed on host; block -> tensor via 16-entry binary search.
// ---------------------------------------------------------------------------
struct CvtArgs {
  const void* src[16];
  short*      dst[16];
  int         n[16];
  int         boff[17];   // prefix block offsets; boff[16] = total blocks
};

__global__ __launch_bounds__(256) void to_bf16_batch(
    CvtArgs a, const unsigned* __restrict__ flag)
{
  const int b = blockIdx.x;
  int lo = 0, hi = 15;
  while (lo < hi){
    const int mid = (lo + hi + 1) >> 1;
    if (b >= a.boff[mid]) lo = mid; else hi = mid - 1;
  }
  const int i   = lo;
  const int idx = (b - a.boff[i])*256 + (int)threadIdx.x;
  if (idx >= a.n[i]) return;
  if (*flag) a.dst[i][idx] = f2b(((const float*)a.src[i])[idx]);
  else       a.dst[i][idx] = ((const short*)a.src[i])[idx];
}

// ---------------------------------------------------------------------------
// GEMM: C[M,N] = bf16( A[M,K] @ W[N,K]^T + bias1[n] (+ bias2[n]) ).
// 128x128 block tile, BK=32, 4 waves, 16x16x32 bf16 MFMA. All dims multiples.
// R16 staging: global_load_lds width=16 into linear LDS [128][32] shorts.
// Wave w covers staging rows w*16..w*16+15 (1KB, dest = base + lane*16).
// Global source chunk pre-swizzled (chunk ^= row&3); frag reads XOR the same
// -> LDS linear, data correct, ds_read conflicts 8-way -> 4-way.
// ---------------------------------------------------------------------------
__global__ __launch_bounds__(256) void gemm_bt(
    const short* __restrict__ A, const short* __restrict__ W,
    short* __restrict__ C, const short* __restrict__ bias1,
    const short* __restrict__ bias2, int N, int K)
{
  __shared__ __align__(16) short lA[128*32];
  __shared__ __align__(16) short lW[128*32];
  const int tid  = threadIdx.x;
  const int lane = tid & 63, wv = tid >> 6;
  const int wm = wv >> 1, wn = wv & 1;
  const int quad = lane >> 4, l15 = lane & 15;
  const long m0 = (long)blockIdx.y * 128, n0 = (long)blockIdx.x * 128;

  float4v acc[4][4];
#pragma unroll
  for (int i=0;i<4;++i)
#pragma unroll
    for (int j=0;j<4;++j) acc[i][j] = (float4v)0.f;

  // staging: wave w, lane l -> row w*16 + l/4, global chunk (l&3)^(row&3)
  const int srow = wv*16 + (lane >> 2);
  const int scol = ((lane & 3) ^ (srow & 3)) * 8;      // pre-swizzled source
  char* lAb = (char*)&lA[0] + wv*1024;                 // wave-uniform dests
  char* lWb = (char*)&lW[0] + wv*1024;
  // frag read: row = .. + l15 -> chunk (quad ^ (l15&3))
  const int rchunk = (quad ^ (l15 & 3)) * 8;

  const int nkt = K >> 5;
  for (int kt = 0; kt < nkt; ++kt) {
    __syncthreads();                       // prev-iter frag reads done
    {
      const short* gA0 = A + (m0 + srow) * (long)K + kt*32 + scol;
      const short* gW0 = W + (n0 + srow) * (long)K + kt*32 + scol;
      gld16(gA0,                lAb);
      gld16(gA0 + 64*(long)K,   lAb + 4096);
      gld16(gW0,                lWb);
      gld16(gW0 + 64*(long)K,   lWb + 4096);
    }
    __syncthreads();                       // drains vmcnt (incl. lds loads)
    short8 af[4], bfr[4];
#pragma unroll
    for (int i=0;i<4;++i) af[i]  = *(const short8*)&lA[(wm*64 + i*16 + l15)*32 + rchunk];
#pragma unroll
    for (int j=0;j<4;++j) bfr[j] = *(const short8*)&lW[(wn*64 + j*16 + l15)*32 + rchunk];
#pragma unroll
    for (int i=0;i<4;++i)
#pragma unroll
      for (int j=0;j<4;++j)
        acc[i][j] = __builtin_amdgcn_mfma_f32_16x16x32_bf16(af[i], bfr[j], acc[i][j], 0, 0, 0);
  }
#pragma unroll
  for (int j=0;j<4;++j){
    const long n = n0 + wn*64 + j*16 + l15;
    float bs = b2f(bias1[n]);
    if (bias2) bs += b2f(bias2[n]);
#pragma unroll
    for (int i=0;i<4;++i){
      const long mb = m0 + wm*64 + i*16 + quad*4;
#pragma unroll
      for (int g=0; g<4; ++g)
        C[(mb+g)*(long)N + n] = f2b(acc[i][j][g] + bs);
    }
  }
}

// ---------------------------------------------------------------------------
// Row-wise LayerNorm (eps=1e-5) + LeakyReLU(0.01) (+ optional pad-mask zero).
// ---------------------------------------------------------------------------
__global__ __launch_bounds__(256) void ln_lrelu(
    const short* __restrict__ X, const short* __restrict__ g,
    const short* __restrict__ be, short* __restrict__ out,
    const int* __restrict__ lens, const int domask)
{
  const int row = blockIdx.x, tid = threadIdx.x;
  const short* xr = X + (size_t)row * 1024;
  short4v xv = *(const short4v*)(xr + tid*4);
  float v[4];
#pragma unroll
  for (int k=0;k<4;++k) v[k] = b2f(xv[k]);
  float s  = v[0]+v[1]+v[2]+v[3];
  float sq = v[0]*v[0]+v[1]*v[1]+v[2]*v[2]+v[3]*v[3];
#pragma unroll
  for (int off=32; off>0; off>>=1){
    s  += __shfl_xor(s,  off, 64);
    sq += __shfl_xor(sq, off, 64);
  }
  __shared__ float red[8];
  if ((tid&63)==0){ red[tid>>6] = s; red[4+(tid>>6)] = sq; }
  __syncthreads();
  s  = red[0]+red[1]+red[2]+red[3];
  sq = red[4]+red[5]+red[6]+red[7];
  const float mean = s * (1.f/1024.f);
  const float var  = sq * (1.f/1024.f) - mean*mean;
  const float rstd = rsqrtf(var + 1e-5f);
  float zmul = 1.f;
  if (domask){ const int b = row >> 9, t = row & 511; if (t >= lens[b]) zmul = 0.f; }
  short4v o;
#pragma unroll
  for (int k=0;k<4;++k){
    const int n = tid*4 + k;
    float y = (v[k]-mean)*rstd*b2f(g[n]) + b2f(be[n]);
    y = (y >= 0.f) ? y : 0.01f*y;
    o[k] = f2b(y * zmul);
  }
  *(short4v*)(out + (size_t)row*1024 + tid*4) = o;
}

// ---------------------------------------------------------------------------
// Persistent bidirectional LSTM scan — R9 structure VERBATIM (frozen; best
// measured: 1725 us/dispatch). Tag-embedded h-state sync. Grid = 32*ndir WGs
// x 256 thr. WG dir = dir0 + (blk>>5); 16 units per WG. Wave w computes gate
// w (torch i,f,g,o); whh A-frags in VGPRs.
// h state global: [dir][buf(step parity)][32 batch][256 pair] u64,
//   hi 32 = tag (epoch<<10 | producing step+1), lo 32 = packed 2xbf16.
// Aligned 8B stores are single-copy atomic: consumers poll the DATA word
// (tag match == payload in hand; the successful spin attempt IS the
// transfer). Two barriers/step; hsh double-buffered; inductive no-clobber.
// ---------------------------------------------------------------------------
__global__ __launch_bounds__(256) void lstm_scan(
    const short* __restrict__ xp, const int xp_cols, const int dir0,
    const short* __restrict__ whh,      // layer base: [2][2048][512]
    u64* __restrict__ hstate,           // [2][2][32][256] tagged u64
    short* __restrict__ hout,           // [32][512][1024]
    const unsigned epoch)
{
  const int wg = blockIdx.x;
  const int dloc = wg >> 5, d = dir0 + dloc;
  const int u0 = (wg & 31) * 16;
  const int tid = threadIdx.x, lane = tid & 63, wv = tid >> 6;
  const int quad = lane >> 4, l15 = lane & 15;

  short8 af[16];
  {
    const short* wr = whh + ((size_t)d*2048 + wv*512 + u0 + l15)*512 + quad*8;
#pragma unroll
    for (int ks=0; ks<16; ++ks) af[ks] = *(const short8*)(wr + ks*32);
  }

  // gate-math ownership: thread = (batch bb, unit-pair pp)
  const int bb = tid >> 3, pp = tid & 7;
  float cstA = 0.f, cstB = 0.f;
  __shared__ __align__(16) unsigned hsh[2][32*260];  // double-buffered staging
  __shared__ float gl[4][16][33];
  const unsigned tbase = epoch << 10;

  for (int step=0; step<512; ++step){
    const int t = d ? (511-step) : step;
    // xp prefetch (overlaps the poll)
    short4v x0, x1;
    {
      const size_t gb = (size_t)dloc*2048 + (size_t)wv*512 + u0 + quad*4;
      x0 = *(const short4v*)(xp + ((size_t)l15*512      + t)*xp_cols + gb);
      x1 = *(const short4v*)(xp + ((size_t)(l15+16)*512 + t)*xp_cols + gb);
    }
    // stage: thread owns unit-pair `tid` of every batch k (lane-consecutive
    // global loads AND lane-consecutive LDS writes -> conflict-free)
    unsigned* stg = &hsh[step&1][tid];
    if (step == 0){
#pragma unroll
      for (int k=0;k<32;++k) stg[k*260] = 0u;        // h_0 = 0, no poll
    } else {
      const u64* hq = hstate + ((size_t)(d*2 + (step&1))<<13) + tid;
      const unsigned tgt = tbase + (unsigned)step;
      u64 v[32];
      for(;;){
        unsigned ok = 1u;
#pragma unroll
        for (int k=0;k<32;++k)
          v[k] = __hip_atomic_load(hq + (size_t)k*256,
                                   __ATOMIC_RELAXED, __HIP_MEMORY_SCOPE_AGENT);
#pragma unroll
        for (int k=0;k<32;++k) ok &= (unsigned)((unsigned)(v[k] >> 32) == tgt);
        if (ok) break;
        __builtin_amdgcn_s_sleep(1);
      }
#pragma unroll
      for (int k=0;k<32;++k) stg[k*260] = (unsigned)v[k];
    }
    __syncthreads();   // B1: staged h ready (also fences prev-step gl reads)

    float4v acc0, acc1;
#pragma unroll
    for (int g=0; g<4; ++g){ acc0[g] = b2f(x0[g]); acc1[g] = b2f(x1[g]); }
    const short* hs = (const short*)&hsh[step&1][0];
#pragma unroll
    for (int ks=0; ks<16; ++ks){
      short8 b0 = *(const short8*)(hs + (size_t)l15*520      + ks*32 + quad*8);
      short8 b1 = *(const short8*)(hs + (size_t)(l15+16)*520 + ks*32 + quad*8);
      acc0 = __builtin_amdgcn_mfma_f32_16x16x32_bf16(af[ks], b0, acc0, 0, 0, 0);
      acc1 = __builtin_amdgcn_mfma_f32_16x16x32_bf16(af[ks], b1, acc1, 0, 0, 0);
    }
#pragma unroll
    for (int g=0; g<4; ++g){
      gl[wv][quad*4+g][l15]    = acc0[g];   // gl[gate][unit 0..15][batch 0..31]
      gl[wv][quad*4+g][l15+16] = acc1[g];
    }
    __syncthreads();   // B2: gl ready (also fences prev-gen hsh buffer reads)

    float hv[2];
#pragma unroll
    for (int i=0; i<2; ++i){
      const int uu = 2*pp + i;
      const float gi = gl[0][uu][bb], gf = gl[1][uu][bb];
      const float gg = gl[2][uu][bb], go = gl[3][uu][bb];
      float& cref = i ? cstB : cstA;
      const float c = sigm(gf)*cref + sigm(gi)*tanh_(gg);
      cref = c;
      hv[i] = sigm(go) * tanh_(c);
    }
    const unsigned hw = (unsigned)(unsigned short)f2b(hv[0])
                      | ((unsigned)(unsigned short)f2b(hv[1]) << 16);
    const u64 pkt = ((u64)(tbase + (unsigned)step + 1u) << 32) | (u64)hw;
    __hip_atomic_store(hstate + ((size_t)(d*2 + ((step+1)&1))<<13)
                         + (size_t)bb*256 + (u0>>1) + pp,
                       pkt, __ATOMIC_RELAXED, __HIP_MEMORY_SCOPE_AGENT);
    *(unsigned*)&hout[((size_t)bb*512 + t)*1024 + d*512 + u0 + 2*pp] = hw;
    // no drain, no flag: the tagged store is self-announcing
  }
}

// ---------------------------------------------------------------------------
// Attention (window_len=1) + classifier. One block per batch element.
// b_u omitted: constant shift cancels in softmax. Output: f32.
// ---------------------------------------------------------------------------
__global__ __launch_bounds__(256) void attn_cls(
    const short* __restrict__ hseq, const short* __restrict__ wu,
    const short* __restrict__ Wc, const short* __restrict__ bc,
    const int* __restrict__ lens, float* __restrict__ out)
{
  const int b = blockIdx.x, tid = threadIdx.x, lane = tid & 63, wv = tid >> 6;
  const int len = lens[b];
  __shared__ float wus[1024];
  __shared__ float sc[512];
  __shared__ float redx[8];
  __shared__ float pooled[1024];
  for (int i=tid; i<1024; i+=256) wus[i] = b2f(wu[i]);
  __syncthreads();
  const short* hb = hseq + (size_t)b*512*1024;
  for (int t=wv; t<512; t+=4){
    const short* hr = hb + (size_t)t*1024;
    float s = 0.f;
#pragma unroll
    for (int j=0;j<16;++j) s += b2f(hr[lane + j*64]) * wus[lane + j*64];
#pragma unroll
    for (int off=32; off>0; off>>=1) s += __shfl_xor(s, off, 64);
    if (lane==0) sc[t] = (t < len) ? s : -3.0e38f;
  }
  __syncthreads();
  float m = -3.0e38f;
  for (int i=tid;i<512;i+=256) m = fmaxf(m, sc[i]);
#pragma unroll
  for (int off=32; off>0; off>>=1) m = fmaxf(m, __shfl_xor(m, off, 64));
  if (lane==0) redx[wv] = m;
  __syncthreads();
  m = fmaxf(fmaxf(redx[0],redx[1]), fmaxf(redx[2],redx[3]));
  float ssum = 0.f;
  for (int i=tid;i<512;i+=256){
    float e = (i<len) ? __expf(sc[i]-m) : 0.f;
    sc[i] = e;
    ssum += e;
  }
#pragma unroll
  for (int off=32; off>0; off>>=1) ssum += __shfl_xor(ssum, off, 64);
  if (lane==0) redx[4+wv] = ssum;
  __syncthreads();
  ssum = redx[4]+redx[5]+redx[6]+redx[7];
  const float inv = 1.f/ssum;
  float4v pa = (float4v)0.f;
  const int k0 = tid*4;
  for (int t=0; t<len; ++t){
    const float a = sc[t];
    short4v hv = *(const short4v*)(hb + (size_t)t*1024 + k0);
    pa[0] += a*b2f(hv[0]); pa[1] += a*b2f(hv[1]);
    pa[2] += a*b2f(hv[2]); pa[3] += a*b2f(hv[3]);
  }
  pooled[k0+0] = pa[0]*inv; pooled[k0+1] = pa[1]*inv;
  pooled[k0+2] = pa[2]*inv; pooled[k0+3] = pa[3]*inv;
  __syncthreads();
  const int j = tid >> 5, l32 = tid & 31;
  float s2 = 0.f;
  for (int kk=l32; kk<1024; kk+=32) s2 += b2f(Wc[j*1024+kk]) * pooled[kk];
#pragma unroll
  for (int off=16; off>0; off>>=1) s2 += __shfl_xor(s2, off, 32);
  if (l32==0) out[b*8+j] = s2 + b2f(bc[j]);
}

// ---------------------------------------------------------------------------
extern "C" void kernel_launch(void* const* d_in, const int* in_sizes, int n_in,
                              void* d_out, int out_size, void* d_ws, size_t ws_size,
                              hipStream_t stream)
{
  (void)in_sizes; (void)n_in; (void)out_size;
  const int*   lens = (const int*)d_in[1];
  float* outp = (float*)d_out;

  const size_t SZ_XP_A = (size_t)16384*4096*2;   // 134,217,728 B
  const size_t SZ_XP_B = (size_t)16384*2048*2;   //  67,108,864 B
  const size_t SZ_H    = (size_t)16384*1024*2;   //  33,554,432 B
  const size_t SZ_HS   = 262144;                 // 4 bufs x 8192 tagged u64
  const size_t SZ_CNT  = 16384;
  const size_t SZ_NORM = 37000000;               // bf16 copies of all inputs
  const bool planA = ws_size >= SZ_XP_A + 2*SZ_H + SZ_HS + SZ_CNT + SZ_NORM;
  const bool planB = !planA && ws_size >= SZ_XP_B + 2*SZ_H + SZ_HS + SZ_CNT + SZ_NORM;
  if (!planA && !planB) return;  // clean failure beats a core dump
  const size_t xpsz = planA ? SZ_XP_A : SZ_XP_B;

  char* ws = (char*)d_ws;
  short*    XP  = (short*)ws;
  short*    HB  = (short*)(ws + xpsz);
  short*    HC  = (short*)(ws + xpsz + SZ_H);
  u64*      HS64= (u64*)(ws + xpsz + 2*SZ_H);
  unsigned* CNT = (unsigned*)(ws + xpsz + 2*SZ_H + SZ_HS);
  unsigned* FLAG = CNT + 4000;
  short*    pool = (short*)(ws + xpsz + 2*SZ_H + SZ_HS + SZ_CNT);

  // carve bf16 copies (128-element aligned)
  size_t off = 0;
  auto carve = [&](size_t n){ short* p = pool + off; off += (n + 127) & ~(size_t)127; return p; };
  short* x   = carve(4194304);
  short* W1  = carve(262144);
  short* b1  = carve(1024);
  short* g1  = carve(1024);
  short* be1 = carve(1024);
  short* W2  = carve(1048576);
  short* b2  = carve(1024);
  short* g2  = carve(1024);
  short* be2 = carve(1024);
  short* wih = carve(8388608);
  short* whh = carve(4194304);
  short* bih = carve(8192);
  short* bhh = carve(8192);
  short* wu  = carve(1024);
  short* Wc  = carve(8192);
  short* bc  = carve(8);

  // zero the tagged h-state once: no garbage tag can match epoch>=1 targets.
  hipMemsetAsync(HS64, 0, SZ_HS, stream);
  detect_f32<<<1, 256, 0, stream>>>((const unsigned short*)d_in[0], FLAG);

  // single batched convert launch for all 16 tensors
  {
    struct { int idx; short* dst; int n; } cv[16] = {
      {0,x,4194304},{2,W1,262144},{3,b1,1024},{4,g1,1024},{5,be1,1024},
      {6,W2,1048576},{7,b2,1024},{8,g2,1024},{9,be2,1024},
      {10,wih,8388608},{11,whh,4194304},{12,bih,8192},{13,bhh,8192},
      {14,wu,1024},{16,Wc,8192},{17,bc,8}
    };
    CvtArgs a;
    int acc = 0;
    for (int i=0;i<16;++i){
      a.src[i]  = d_in[cv[i].idx];
      a.dst[i]  = cv[i].dst;
      a.n[i]    = cv[i].n;
      a.boff[i] = acc;
      acc += (cv[i].n + 255) / 256;
    }
    a.boff[16] = acc;
    to_bf16_batch<<<acc, 256, 0, stream>>>(a, FLAG);
  }

  dim3 blk(256);
  // extract MLP
  gemm_bt<<<dim3(8,128),  blk, 0, stream>>>(x,  W1, XP, b1, nullptr, 1024, 256);
  ln_lrelu<<<16384, blk, 0, stream>>>(XP, g1, be1, HB, lens, 0);
  gemm_bt<<<dim3(8,128),  blk, 0, stream>>>(HB, W2, XP, b2, nullptr, 1024, 1024);
  ln_lrelu<<<16384, blk, 0, stream>>>(XP, g2, be2, HC, lens, 1);   // + pad mask

  const short* lin[2]  = { HC, HB };   // layer inputs
  short*       lout[2] = { HB, HC };   // layer outputs
  for (int l = 0; l < 2; ++l){
    const short* whh_l = whh + (size_t)l*2*2048*512;
    if (planA){
      gemm_bt<<<dim3(32,128), blk, 0, stream>>>(
          lin[l], wih + (size_t)l*4096*1024, XP,
          bih + l*4096, bhh + l*4096, 4096, 1024);
      lstm_scan<<<64, blk, 0, stream>>>(XP, 4096, 0, whh_l, HS64, lout[l],
                                        (unsigned)(l+1));
    } else {
      for (int d = 0; d < 2; ++d){
        gemm_bt<<<dim3(16,128), blk, 0, stream>>>(
            lin[l], wih + ((size_t)(l*2+d))*2048*1024, XP,
            bih + (l*2+d)*2048, bhh + (l*2+d)*2048, 2048, 1024);
        lstm_scan<<<32, blk, 0, stream>>>(XP, 2048, d, whh_l, HS64, lout[l],
                                          (unsigned)(l+1));
      }
    }
  }
  // attention + classifier
  attn_cls<<<32, blk, 0, stream>>>(HC, wu, Wc, bc, lens, outp);
}

// Round 10
// 4183.145 us; speedup vs baseline: 1.1163x; 1.0042x over previous
//
#include <hip/hip_runtime.h>
#include <stdint.h>
#include <stddef.h>

// Problem constants: B=32, T=512, FD=256, NH=1024, NC=512, NOUT=8
// Established: device inputs f32; output f32; R4-R16 passed (absmax 3.9e-3).
// R18: R17 epilogue bug fix. R17's readback covered only half of C's columns
//      (256 threads x 1 short8 = 2048 shorts vs 4096 needed per i-slice) ->
//      absmax 0.45. Fix: each thread reads TWO adjacent short8 (erd, erd+8)
//      and issues two 16B stores = 32B contiguous per lane, full coverage.
//      Everything else identical to R17: scan frozen at R9-verbatim, gld16
//      staging (R16), batched converts, LDS-transposed coalesced C-write.

typedef short  short8  __attribute__((ext_vector_type(8)));
typedef short  short4v __attribute__((ext_vector_type(4)));
typedef float  float4v __attribute__((ext_vector_type(4)));
typedef unsigned long long u64;

__device__ inline float b2f(short x){
  union { unsigned u; float f; } v; v.u = ((unsigned)(unsigned short)x) << 16; return v.f;
}
__device__ inline short f2b(float f){
  union { float f; unsigned u; } v; v.f = f;
  unsigned r = (v.u + 0x7fffu + ((v.u >> 16) & 1u)) >> 16;
  return (short)r;
}
__device__ inline float sigm(float x){ return 1.f / (1.f + __expf(-x)); }
__device__ inline float tanh_(float x){ return 2.f / (1.f + __expf(-2.f*x)) - 1.f; }

// async global->LDS, 16B per lane; LDS dest is wave-uniform base + lane*16.
typedef const __attribute__((address_space(1))) unsigned gu32;
typedef __attribute__((address_space(3))) unsigned lu32;
__device__ inline void gld16(const void* g, void* l){
  __builtin_amdgcn_global_load_lds((gu32*)g, (lu32*)l, 16, 0, 0);
}

// ---------------------------------------------------------------------------
// Input dtype detection: true-bf16 normals never have exponent >= 0xC0;
// f32 low half-words are uniform -> ~25% exceed.
// ---------------------------------------------------------------------------
__global__ __launch_bounds__(256) void detect_f32(
    const unsigned short* __restrict__ p, unsigned* __restrict__ flag)
{
  const int tid = threadIdx.x;
  unsigned h = 0;
  for (int i = tid; i < 1024; i += 256){
    const unsigned e = (p[i] >> 7) & 0xFFu;
    if (e >= 0xC0u) ++h;
  }
#pragma unroll
  for (int off=32; off>0; off>>=1) h += __shfl_xor(h, off, 64);
  __shared__ unsigned sh[4];
  if ((tid&63)==0) sh[tid>>6] = h;
  __syncthreads();
  if (tid==0) *flag = (sh[0]+sh[1]+sh[2]+sh[3] >= 8u) ? 1u : 0u;
}

// ---------------------------------------------------------------------------
// Batched bf16 normalization: all 16 tensors in ONE launch. Per-tensor block
// ranges precomputed on host; block -> tensor via 16-entry binary search.
// ---------------------------------------------------------------------------
struct CvtArgs {
  const void* src[16];
  short*      dst[16];
  int         n[16];
  int         boff[17];   // prefix block offsets; boff[16] = total blocks
};

__global__ __launch_bounds__(256) void to_bf16_batch(
    CvtArgs a, const unsigned* __restrict__ flag)
{
  const int b = blockIdx.x;
  int lo = 0, hi = 15;
  while (lo < hi){
    const int mid = (lo + hi + 1) >> 1;
    if (b >= a.boff[mid]) lo = mid; else hi = mid - 1;
  }
  const int i   = lo;
  const int idx = (b - a.boff[i])*256 + (int)threadIdx.x;
  if (idx >= a.n[i]) return;
  if (*flag) a.dst[i][idx] = f2b(((const float*)a.src[i])[idx]);
  else       a.dst[i][idx] = ((const short*)a.src[i])[idx];
}

// ---------------------------------------------------------------------------
// GEMM: C[M,N] = bf16( A[M,K] @ W[N,K]^T + bias1[n] (+ bias2[n]) ).
// 128x128 block tile, BK=32, 4 waves, 16x16x32 bf16 MFMA. All dims multiples.
// Staging: global_load_lds width=16 into linear LDS [128][32] shorts,
// pre-swizzled global source + XOR frag read (R16). Epilogue: LDS-transposed
// coalesced C-write (R18: two short8 per thread -> full column coverage).
// ---------------------------------------------------------------------------
__global__ __launch_bounds__(256) void gemm_bt(
    const short* __restrict__ A, const short* __restrict__ W,
    short* __restrict__ C, const short* __restrict__ bias1,
    const short* __restrict__ bias2, int N, int K)
{
  __shared__ __align__(16) short lA[128*32];
  __shared__ __align__(16) short lW[128*32];
  __shared__ __align__(16) short eps[2*16*136];   // epilogue transpose buffer
  const int tid  = threadIdx.x;
  const int lane = tid & 63, wv = tid >> 6;
  const int wm = wv >> 1, wn = wv & 1;
  const int quad = lane >> 4, l15 = lane & 15;
  const long m0 = (long)blockIdx.y * 128, n0 = (long)blockIdx.x * 128;

  float4v acc[4][4];
#pragma unroll
  for (int i=0;i<4;++i)
#pragma unroll
    for (int j=0;j<4;++j) acc[i][j] = (float4v)0.f;

  // staging: wave w, lane l -> row w*16 + l/4, global chunk (l&3)^(row&3)
  const int srow = wv*16 + (lane >> 2);
  const int scol = ((lane & 3) ^ (srow & 3)) * 8;      // pre-swizzled source
  char* lAb = (char*)&lA[0] + wv*1024;                 // wave-uniform dests
  char* lWb = (char*)&lW[0] + wv*1024;
  // frag read: row = .. + l15 -> chunk (quad ^ (l15&3))
  const int rchunk = (quad ^ (l15 & 3)) * 8;

  const int nkt = K >> 5;
  for (int kt = 0; kt < nkt; ++kt) {
    __syncthreads();                       // prev-iter frag reads done
    {
      const short* gA0 = A + (m0 + srow) * (long)K + kt*32 + scol;
      const short* gW0 = W + (n0 + srow) * (long)K + kt*32 + scol;
      gld16(gA0,                lAb);
      gld16(gA0 + 64*(long)K,   lAb + 4096);
      gld16(gW0,                lWb);
      gld16(gW0 + 64*(long)K,   lWb + 4096);
    }
    __syncthreads();                       // drains vmcnt (incl. lds loads)
    short8 af[4], bfr[4];
#pragma unroll
    for (int i=0;i<4;++i) af[i]  = *(const short8*)&lA[(wm*64 + i*16 + l15)*32 + rchunk];
#pragma unroll
    for (int j=0;j<4;++j) bfr[j] = *(const short8*)&lW[(wn*64 + j*16 + l15)*32 + rchunk];
#pragma unroll
    for (int i=0;i<4;++i)
#pragma unroll
      for (int j=0;j<4;++j)
        acc[i][j] = __builtin_amdgcn_mfma_f32_16x16x32_bf16(af[i], bfr[j], acc[i][j], 0, 0, 0);
  }

  // epilogue: per i-slice, acc+bias -> eps[wm][quad*4+g][wn*64+j*16+l15],
  // barrier, coalesced readback: each thread 2x short8 (32B contiguous).
  float bs[4];
#pragma unroll
  for (int j=0;j<4;++j){
    const long n = n0 + wn*64 + j*16 + l15;
    bs[j] = b2f(bias1[n]);
    if (bias2) bs[j] += b2f(bias2[n]);
  }
  const int eh = tid >> 7, er = (tid >> 3) & 15, ec = tid & 7;
  short* erd = &eps[(eh*16 + er)*136 + ec*16];
  short* ewr = &eps[wm*16*136 + wn*64 + l15];
#pragma unroll
  for (int i=0;i<4;++i){
    if (i) __syncthreads();                // eps reuse fence
#pragma unroll
    for (int j=0;j<4;++j)
#pragma unroll
      for (int g=0; g<4; ++g)
        ewr[(quad*4+g)*136 + j*16] = f2b(acc[i][j][g] + bs[j]);
    __syncthreads();                       // eps ready
    short8 v0 = *(const short8*)erd;
    short8 v1 = *(const short8*)(erd + 8);
    short* cp = &C[(m0 + eh*64 + i*16 + er)*(long)N + n0 + ec*16];
    *(short8*)cp       = v0;
    *(short8*)(cp + 8) = v1;
  }
}

// ---------------------------------------------------------------------------
// Row-wise LayerNorm (eps=1e-5) + LeakyReLU(0.01) (+ optional pad-mask zero).
// ---------------------------------------------------------------------------
__global__ __launch_bounds__(256) void ln_lrelu(
    const short* __restrict__ X, const short* __restrict__ g,
    const short* __restrict__ be, short* __restrict__ out,
    const int* __restrict__ lens, const int domask)
{
  const int row = blockIdx.x, tid = threadIdx.x;
  const short* xr = X + (size_t)row * 1024;
  short4v xv = *(const short4v*)(xr + tid*4);
  float v[4];
#pragma unroll
  for (int k=0;k<4;++k) v[k] = b2f(xv[k]);
  float s  = v[0]+v[1]+v[2]+v[3];
  float sq = v[0]*v[0]+v[1]*v[1]+v[2]*v[2]+v[3]*v[3];
#pragma unroll
  for (int off=32; off>0; off>>=1){
    s  += __shfl_xor(s,  off, 64);
    sq += __shfl_xor(sq, off, 64);
  }
  __shared__ float red[8];
  if ((tid&63)==0){ red[tid>>6] = s; red[4+(tid>>6)] = sq; }
  __syncthreads();
  s  = red[0]+red[1]+red[2]+red[3];
  sq = red[4]+red[5]+red[6]+red[7];
  const float mean = s * (1.f/1024.f);
  const float var  = sq * (1.f/1024.f) - mean*mean;
  const float rstd = rsqrtf(var + 1e-5f);
  float zmul = 1.f;
  if (domask){ const int b = row >> 9, t = row & 511; if (t >= lens[b]) zmul = 0.f; }
  short4v o;
#pragma unroll
  for (int k=0;k<4;++k){
    const int n = tid*4 + k;
    float y = (v[k]-mean)*rstd*b2f(g[n]) + b2f(be[n]);
    y = (y >= 0.f) ? y : 0.01f*y;
    o[k] = f2b(y * zmul);
  }
  *(short4v*)(out + (size_t)row*1024 + tid*4) = o;
}

// ---------------------------------------------------------------------------
// Persistent bidirectional LSTM scan — R9 structure VERBATIM (frozen; best
// measured: 1725 us/dispatch). Tag-embedded h-state sync. Grid = 32*ndir WGs
// x 256 thr. WG dir = dir0 + (blk>>5); 16 units per WG. Wave w computes gate
// w (torch i,f,g,o); whh A-frags in VGPRs.
// h state global: [dir][buf(step parity)][32 batch][256 pair] u64,
//   hi 32 = tag (epoch<<10 | producing step+1), lo 32 = packed 2xbf16.
// Aligned 8B stores are single-copy atomic: consumers poll the DATA word
// (tag match == payload in hand; the successful spin attempt IS the
// transfer). Two barriers/step; hsh double-buffered; inductive no-clobber.
// ---------------------------------------------------------------------------
__global__ __launch_bounds__(256) void lstm_scan(
    const short* __restrict__ xp, const int xp_cols, const int dir0,
    const short* __restrict__ whh,      // layer base: [2][2048][512]
    u64* __restrict__ hstate,           // [2][2][32][256] tagged u64
    short* __restrict__ hout,           // [32][512][1024]
    const unsigned epoch)
{
  const int wg = blockIdx.x;
  const int dloc = wg >> 5, d = dir0 + dloc;
  const int u0 = (wg & 31) * 16;
  const int tid = threadIdx.x, lane = tid & 63, wv = tid >> 6;
  const int quad = lane >> 4, l15 = lane & 15;

  short8 af[16];
  {
    const short* wr = whh + ((size_t)d*2048 + wv*512 + u0 + l15)*512 + quad*8;
#pragma unroll
    for (int ks=0; ks<16; ++ks) af[ks] = *(const short8*)(wr + ks*32);
  }

  // gate-math ownership: thread = (batch bb, unit-pair pp)
  const int bb = tid >> 3, pp = tid & 7;
  float cstA = 0.f, cstB = 0.f;
  __shared__ __align__(16) unsigned hsh[2][32*260];  // double-buffered staging
  __shared__ float gl[4][16][33];
  const unsigned tbase = epoch << 10;

  for (int step=0; step<512; ++step){
    const int t = d ? (511-step) : step;
    // xp prefetch (overlaps the poll)
    short4v x0, x1;
    {
      const size_t gb = (size_t)dloc*2048 + (size_t)wv*512 + u0 + quad*4;
      x0 = *(const short4v*)(xp + ((size_t)l15*512      + t)*xp_cols + gb);
      x1 = *(const short4v*)(xp + ((size_t)(l15+16)*512 + t)*xp_cols + gb);
    }
    // stage: thread owns unit-pair `tid` of every batch k (lane-consecutive
    // global loads AND lane-consecutive LDS writes -> conflict-free)
    unsigned* stg = &hsh[step&1][tid];
    if (step == 0){
#pragma unroll
      for (int k=0;k<32;++k) stg[k*260] = 0u;        // h_0 = 0, no poll
    } else {
      const u64* hq = hstate + ((size_t)(d*2 + (step&1))<<13) + tid;
      const unsigned tgt = tbase + (unsigned)step;
      u64 v[32];
      for(;;){
        unsigned ok = 1u;
#pragma unroll
        for (int k=0;k<32;++k)
          v[k] = __hip_atomic_load(hq + (size_t)k*256,
                                   __ATOMIC_RELAXED, __HIP_MEMORY_SCOPE_AGENT);
#pragma unroll
        for (int k=0;k<32;++k) ok &= (unsigned)((unsigned)(v[k] >> 32) == tgt);
        if (ok) break;
        __builtin_amdgcn_s_sleep(1);
      }
#pragma unroll
      for (int k=0;k<32;++k) stg[k*260] = (unsigned)v[k];
    }
    __syncthreads();   // B1: staged h ready (also fences prev-step gl reads)

    float4v acc0, acc1;
#pragma unroll
    for (int g=0; g<4; ++g){ acc0[g] = b2f(x0[g]); acc1[g] = b2f(x1[g]); }
    const short* hs = (const short*)&hsh[step&1][0];
#pragma unroll
    for (int ks=0; ks<16; ++ks){
      short8 b0 = *(const short8*)(hs + (size_t)l15*520      + ks*32 + quad*8);
      short8 b1 = *(const short8*)(hs + (size_t)(l15+16)*520 + ks*32 + quad*8);
      acc0 = __builtin_amdgcn_mfma_f32_16x16x32_bf16(af[ks], b0, acc0, 0, 0, 0);
      acc1 = __builtin_amdgcn_mfma_f32_16x16x32_bf16(af[ks], b1, acc1, 0, 0, 0);
    }
#pragma unroll
    for (int g=0; g<4; ++g){
      gl[wv][quad*4+g][l15]    = acc0[g];   // gl[gate][unit 0..15][batch 0..31]
      gl[wv][quad*4+g][l15+16] = acc1[g];
    }
    __syncthreads();   // B2: gl ready (also fences prev-gen hsh buffer reads)

    float hv[2];
#pragma unroll
    for (int i=0; i<2; ++i){
      const int uu = 2*pp + i;
      const float gi = gl[0][uu][bb], gf = gl[1][uu][bb];
      const float gg = gl[2][uu][bb], go = gl[3][uu][bb];
      float& cref = i ? cstB : cstA;
      const float c = sigm(gf)*cref + sigm(gi)*tanh_(gg);
      cref = c;
      hv[i] = sigm(go) * tanh_(c);
    }
    const unsigned hw = (unsigned)(unsigned short)f2b(hv[0])
                      | ((unsigned)(unsigned short)f2b(hv[1]) << 16);
    const u64 pkt = ((u64)(tbase + (unsigned)step + 1u) << 32) | (u64)hw;
    __hip_atomic_store(hstate + ((size_t)(d*2 + ((step+1)&1))<<13)
                         + (size_t)bb*256 + (u0>>1) + pp,
                       pkt, __ATOMIC_RELAXED, __HIP_MEMORY_SCOPE_AGENT);
    *(unsigned*)&hout[((size_t)bb*512 + t)*1024 + d*512 + u0 + 2*pp] = hw;
    // no drain, no flag: the tagged store is self-announcing
  }
}

// ---------------------------------------------------------------------------
// Attention (window_len=1) + classifier. One block per batch element.
// b_u omitted: constant shift cancels in softmax. Output: f32.
// ---------------------------------------------------------------------------
__global__ __launch_bounds__(256) void attn_cls(
    const short* __restrict__ hseq, const short* __restrict__ wu,
    const short* __restrict__ Wc, const short* __restrict__ bc,
    const int* __restrict__ lens, float* __restrict__ out)
{
  const int b = blockIdx.x, tid = threadIdx.x, lane = tid & 63, wv = tid >> 6;
  const int len = lens[b];
  __shared__ float wus[1024];
  __shared__ float sc[512];
  __shared__ float redx[8];
  __shared__ float pooled[1024];
  for (int i=tid; i<1024; i+=256) wus[i] = b2f(wu[i]);
  __syncthreads();
  const short* hb = hseq + (size_t)b*512*1024;
  for (int t=wv; t<512; t+=4){
    const short* hr = hb + (size_t)t*1024;
    float s = 0.f;
#pragma unroll
    for (int j=0;j<16;++j) s += b2f(hr[lane + j*64]) * wus[lane + j*64];
#pragma unroll
    for (int off=32; off>0; off>>=1) s += __shfl_xor(s, off, 64);
    if (lane==0) sc[t] = (t < len) ? s : -3.0e38f;
  }
  __syncthreads();
  float m = -3.0e38f;
  for (int i=tid;i<512;i+=256) m = fmaxf(m, sc[i]);
#pragma unroll
  for (int off=32; off>0; off>>=1) m = fmaxf(m, __shfl_xor(m, off, 64));
  if (lane==0) redx[wv] = m;
  __syncthreads();
  m = fmaxf(fmaxf(redx[0],redx[1]), fmaxf(redx[2],redx[3]));
  float ssum = 0.f;
  for (int i=tid;i<512;i+=256){
    float e = (i<len) ? __expf(sc[i]-m) : 0.f;
    sc[i] = e;
    ssum += e;
  }
#pragma unroll
  for (int off=32; off>0; off>>=1) ssum += __shfl_xor(ssum, off, 64);
  if (lane==0) redx[4+wv] = ssum;
  __syncthreads();
  ssum = redx[4]+redx[5]+redx[6]+redx[7];
  const float inv = 1.f/ssum;
  float4v pa = (float4v)0.f;
  const int k0 = tid*4;
  for (int t=0; t<len; ++t){
    const float a = sc[t];
    short4v hv = *(const short4v*)(hb + (size_t)t*1024 + k0);
    pa[0] += a*b2f(hv[0]); pa[1] += a*b2f(hv[1]);
    pa[2] += a*b2f(hv[2]); pa[3] += a*b2f(hv[3]);
  }
  pooled[k0+0] = pa[0]*inv; pooled[k0+1] = pa[1]*inv;
  pooled[k0+2] = pa[2]*inv; pooled[k0+3] = pa[3]*inv;
  __syncthreads();
  const int j = tid >> 5, l32 = tid & 31;
  float s2 = 0.f;
  for (int kk=l32; kk<1024; kk+=32) s2 += b2f(Wc[j*1024+kk]) * pooled[kk];
#pragma unroll
  for (int off=16; off>0; off>>=1) s2 += __shfl_xor(s2, off, 32);
  if (l32==0) out[b*8+j] = s2 + b2f(bc[j]);
}

// ---------------------------------------------------------------------------
extern "C" void kernel_launch(void* const* d_in, const int* in_sizes, int n_in,
                              void* d_out, int out_size, void* d_ws, size_t ws_size,
                              hipStream_t stream)
{
  (void)in_sizes; (void)n_in; (void)out_size;
  const int*   lens = (const int*)d_in[1];
  float* outp = (float*)d_out;

  const size_t SZ_XP_A = (size_t)16384*4096*2;   // 134,217,728 B
  const size_t SZ_XP_B = (size_t)16384*2048*2;   //  67,108,864 B
  const size_t SZ_H    = (size_t)16384*1024*2;   //  33,554,432 B
  const size_t SZ_HS   = 262144;                 // 4 bufs x 8192 tagged u64
  const size_t SZ_CNT  = 16384;
  const size_t SZ_NORM = 37000000;               // bf16 copies of all inputs
  const bool planA = ws_size >= SZ_XP_A + 2*SZ_H + SZ_HS + SZ_CNT + SZ_NORM;
  const bool planB = !planA && ws_size >= SZ_XP_B + 2*SZ_H + SZ_HS + SZ_CNT + SZ_NORM;
  if (!planA && !planB) return;  // clean failure beats a core dump
  const size_t xpsz = planA ? SZ_XP_A : SZ_XP_B;

  char* ws = (char*)d_ws;
  short*    XP  = (short*)ws;
  short*    HB  = (short*)(ws + xpsz);
  short*    HC  = (short*)(ws + xpsz + SZ_H);
  u64*      HS64= (u64*)(ws + xpsz + 2*SZ_H);
  unsigned* CNT = (unsigned*)(ws + xpsz + 2*SZ_H + SZ_HS);
  unsigned* FLAG = CNT + 4000;
  short*    pool = (short*)(ws + xpsz + 2*SZ_H + SZ_HS + SZ_CNT);

  // carve bf16 copies (128-element aligned)
  size_t off = 0;
  auto carve = [&](size_t n){ short* p = pool + off; off += (n + 127) & ~(size_t)127; return p; };
  short* x   = carve(4194304);
  short* W1  = carve(262144);
  short* b1  = carve(1024);
  short* g1  = carve(1024);
  short* be1 = carve(1024);
  short* W2  = carve(1048576);
  short* b2  = carve(1024);
  short* g2  = carve(1024);
  short* be2 = carve(1024);
  short* wih = carve(8388608);
  short* whh = carve(4194304);
  short* bih = carve(8192);
  short* bhh = carve(8192);
  short* wu  = carve(1024);
  short* Wc  = carve(8192);
  short* bc  = carve(8);

  // zero the tagged h-state once: no garbage tag can match epoch>=1 targets.
  hipMemsetAsync(HS64, 0, SZ_HS, stream);
  detect_f32<<<1, 256, 0, stream>>>((const unsigned short*)d_in[0], FLAG);

  // single batched convert launch for all 16 tensors
  {
    struct { int idx; short* dst; int n; } cv[16] = {
      {0,x,4194304},{2,W1,262144},{3,b1,1024},{4,g1,1024},{5,be1,1024},
      {6,W2,1048576},{7,b2,1024},{8,g2,1024},{9,be2,1024},
      {10,wih,8388608},{11,whh,4194304},{12,bih,8192},{13,bhh,8192},
      {14,wu,1024},{16,Wc,8192},{17,bc,8}
    };
    CvtArgs a;
    int acc = 0;
    for (int i=0;i<16;++i){
      a.src[i]  = d_in[cv[i].idx];
      a.dst[i]  = cv[i].dst;
      a.n[i]    = cv[i].n;
      a.boff[i] = acc;
      acc += (cv[i].n + 255) / 256;
    }
    a.boff[16] = acc;
    to_bf16_batch<<<acc, 256, 0, stream>>>(a, FLAG);
  }

  dim3 blk(256);
  // extract MLP
  gemm_bt<<<dim3(8,128),  blk, 0, stream>>>(x,  W1, XP, b1, nullptr, 1024, 256);
  ln_lrelu<<<16384, blk, 0, stream>>>(XP, g1, be1, HB, lens, 0);
  gemm_bt<<<dim3(8,128),  blk, 0, stream>>>(HB, W2, XP, b2, nullptr, 1024, 1024);
  ln_lrelu<<<16384, blk, 0, stream>>>(XP, g2, be2, HC, lens, 1);   // + pad mask

  const short* lin[2]  = { HC, HB };   // layer inputs
  short*       lout[2] = { HB, HC };   // layer outputs
  for (int l = 0; l < 2; ++l){
    const short* whh_l = whh + (size_t)l*2*2048*512;
    if (planA){
      gemm_bt<<<dim3(32,128), blk, 0, stream>>>(
          lin[l], wih + (size_t)l*4096*1024, XP,
          bih + l*4096, bhh + l*4096, 4096, 1024);
      lstm_scan<<<64, blk, 0, stream>>>(XP, 4096, 0, whh_l, HS64, lout[l],
                                        (unsigned)(l+1));
    } else {
      for (int d = 0; d < 2; ++d){
        gemm_bt<<<dim3(16,128), blk, 0, stream>>>(
            lin[l], wih + ((size_t)(l*2+d))*2048*1024, XP,
            bih + (l*2+d)*2048, bhh + (l*2+d)*2048, 2048, 1024);
        lstm_scan<<<32, blk, 0, stream>>>(XP, 2048, d, whh_l, HS64, lout[l],
                                          (unsigned)(l+1));
      }
    }
  }
  // attention + classifier
  attn_cls<<<32, blk, 0, stream>>>(HC, wu, Wc, bc, lens, outp);
}

// Round 11
// 4112.346 us; speedup vs baseline: 1.1355x; 1.0172x over previous
//
#include <hip/hip_runtime.h>
#include <stdint.h>
#include <stddef.h>

// Problem constants: B=32, T=512, FD=256, NH=1024, NC=512, NOUT=8
// Established: device inputs f32; output f32; R4-R18 passed (absmax 3.9e-3).
// R19: attention tail parallelized. Old attn_cls used 32 blocks (32/256 CUs)
//      to stream 64MB of HC (score pass + pooled pass) -> ~1/8 chip BW.
//      Split: attn_scores (256 blk) -> attn_softmax (32 blk, tiny) ->
//      attn_pool (256 blk) -> attn_cls2 (32 blk, tiny). Scratch lives in XP
//      (dead after scan1). alpha[t]=0 for t>=len keeps math identical.
//      Scan frozen at R9-verbatim; gemm/ln/converts identical to R18.

typedef short  short8  __attribute__((ext_vector_type(8)));
typedef short  short4v __attribute__((ext_vector_type(4)));
typedef float  float4v __attribute__((ext_vector_type(4)));
typedef unsigned long long u64;

__device__ inline float b2f(short x){
  union { unsigned u; float f; } v; v.u = ((unsigned)(unsigned short)x) << 16; return v.f;
}
__device__ inline short f2b(float f){
  union { float f; unsigned u; } v; v.f = f;
  unsigned r = (v.u + 0x7fffu + ((v.u >> 16) & 1u)) >> 16;
  return (short)r;
}
__device__ inline float sigm(float x){ return 1.f / (1.f + __expf(-x)); }
__device__ inline float tanh_(float x){ return 2.f / (1.f + __expf(-2.f*x)) - 1.f; }

// async global->LDS, 16B per lane; LDS dest is wave-uniform base + lane*16.
typedef const __attribute__((address_space(1))) unsigned gu32;
typedef __attribute__((address_space(3))) unsigned lu32;
__device__ inline void gld16(const void* g, void* l){
  __builtin_amdgcn_global_load_lds((gu32*)g, (lu32*)l, 16, 0, 0);
}

// ---------------------------------------------------------------------------
// Input dtype detection: true-bf16 normals never have exponent >= 0xC0;
// f32 low half-words are uniform -> ~25% exceed.
// ---------------------------------------------------------------------------
__global__ __launch_bounds__(256) void detect_f32(
    const unsigned short* __restrict__ p, unsigned* __restrict__ flag)
{
  const int tid = threadIdx.x;
  unsigned h = 0;
  for (int i = tid; i < 1024; i += 256){
    const unsigned e = (p[i] >> 7) & 0xFFu;
    if (e >= 0xC0u) ++h;
  }
#pragma unroll
  for (int off=32; off>0; off>>=1) h += __shfl_xor(h, off, 64);
  __shared__ unsigned sh[4];
  if ((tid&63)==0) sh[tid>>6] = h;
  __syncthreads();
  if (tid==0) *flag = (sh[0]+sh[1]+sh[2]+sh[3] >= 8u) ? 1u : 0u;
}

// ---------------------------------------------------------------------------
// Batched bf16 normalization: all 16 tensors in ONE launch. Per-tensor block
// ranges precomputed on host; block -> tensor via 16-entry binary search.
// ---------------------------------------------------------------------------
struct CvtArgs {
  const void* src[16];
  short*      dst[16];
  int         n[16];
  int         boff[17];   // prefix block offsets; boff[16] = total blocks
};

__global__ __launch_bounds__(256) void to_bf16_batch(
    CvtArgs a, const unsigned* __restrict__ flag)
{
  const int b = blockIdx.x;
  int lo = 0, hi = 15;
  while (lo < hi){
    const int mid = (lo + hi + 1) >> 1;
    if (b >= a.boff[mid]) lo = mid; else hi = mid - 1;
  }
  const int i   = lo;
  const int idx = (b - a.boff[i])*256 + (int)threadIdx.x;
  if (idx >= a.n[i]) return;
  if (*flag) a.dst[i][idx] = f2b(((const float*)a.src[i])[idx]);
  else       a.dst[i][idx] = ((const short*)a.src[i])[idx];
}

// ---------------------------------------------------------------------------
// GEMM: C[M,N] = bf16( A[M,K] @ W[N,K]^T + bias1[n] (+ bias2[n]) ).
// 128x128 block tile, BK=32, 4 waves, 16x16x32 bf16 MFMA. All dims multiples.
// Staging: global_load_lds width=16 into linear LDS [128][32] shorts,
// pre-swizzled global source + XOR frag read (R16). Epilogue: LDS-transposed
// coalesced C-write (R18: two short8 per thread -> full column coverage).
// ---------------------------------------------------------------------------
__global__ __launch_bounds__(256) void gemm_bt(
    const short* __restrict__ A, const short* __restrict__ W,
    short* __restrict__ C, const short* __restrict__ bias1,
    const short* __restrict__ bias2, int N, int K)
{
  __shared__ __align__(16) short lA[128*32];
  __shared__ __align__(16) short lW[128*32];
  __shared__ __align__(16) short eps[2*16*136];   // epilogue transpose buffer
  const int tid  = threadIdx.x;
  const int lane = tid & 63, wv = tid >> 6;
  const int wm = wv >> 1, wn = wv & 1;
  const int quad = lane >> 4, l15 = lane & 15;
  const long m0 = (long)blockIdx.y * 128, n0 = (long)blockIdx.x * 128;

  float4v acc[4][4];
#pragma unroll
  for (int i=0;i<4;++i)
#pragma unroll
    for (int j=0;j<4;++j) acc[i][j] = (float4v)0.f;

  // staging: wave w, lane l -> row w*16 + l/4, global chunk (l&3)^(row&3)
  const int srow = wv*16 + (lane >> 2);
  const int scol = ((lane & 3) ^ (srow & 3)) * 8;      // pre-swizzled source
  char* lAb = (char*)&lA[0] + wv*1024;                 // wave-uniform dests
  char* lWb = (char*)&lW[0] + wv*1024;
  // frag read: row = .. + l15 -> chunk (quad ^ (l15&3))
  const int rchunk = (quad ^ (l15 & 3)) * 8;

  const int nkt = K >> 5;
  for (int kt = 0; kt < nkt; ++kt) {
    __syncthreads();                       // prev-iter frag reads done
    {
      const short* gA0 = A + (m0 + srow) * (long)K + kt*32 + scol;
      const short* gW0 = W + (n0 + srow) * (long)K + kt*32 + scol;
      gld16(gA0,                lAb);
      gld16(gA0 + 64*(long)K,   lAb + 4096);
      gld16(gW0,                lWb);
      gld16(gW0 + 64*(long)K,   lWb + 4096);
    }
    __syncthreads();                       // drains vmcnt (incl. lds loads)
    short8 af[4], bfr[4];
#pragma unroll
    for (int i=0;i<4;++i) af[i]  = *(const short8*)&lA[(wm*64 + i*16 + l15)*32 + rchunk];
#pragma unroll
    for (int j=0;j<4;++j) bfr[j] = *(const short8*)&lW[(wn*64 + j*16 + l15)*32 + rchunk];
#pragma unroll
    for (int i=0;i<4;++i)
#pragma unroll
      for (int j=0;j<4;++j)
        acc[i][j] = __builtin_amdgcn_mfma_f32_16x16x32_bf16(af[i], bfr[j], acc[i][j], 0, 0, 0);
  }

  // epilogue: per i-slice, acc+bias -> eps[wm][quad*4+g][wn*64+j*16+l15],
  // barrier, coalesced readback: each thread 2x short8 (32B contiguous).
  float bs[4];
#pragma unroll
  for (int j=0;j<4;++j){
    const long n = n0 + wn*64 + j*16 + l15;
    bs[j] = b2f(bias1[n]);
    if (bias2) bs[j] += b2f(bias2[n]);
  }
  const int eh = tid >> 7, er = (tid >> 3) & 15, ec = tid & 7;
  short* erd = &eps[(eh*16 + er)*136 + ec*16];
  short* ewr = &eps[wm*16*136 + wn*64 + l15];
#pragma unroll
  for (int i=0;i<4;++i){
    if (i) __syncthreads();                // eps reuse fence
#pragma unroll
    for (int j=0;j<4;++j)
#pragma unroll
      for (int g=0; g<4; ++g)
        ewr[(quad*4+g)*136 + j*16] = f2b(acc[i][j][g] + bs[j]);
    __syncthreads();                       // eps ready
    short8 v0 = *(const short8*)erd;
    short8 v1 = *(const short8*)(erd + 8);
    short* cp = &C[(m0 + eh*64 + i*16 + er)*(long)N + n0 + ec*16];
    *(short8*)cp       = v0;
    *(short8*)(cp + 8) = v1;
  }
}

// ---------------------------------------------------------------------------
// Row-wise LayerNorm (eps=1e-5) + LeakyReLU(0.01) (+ optional pad-mask zero).
// ---------------------------------------------------------------------------
__global__ __launch_bounds__(256) void ln_lrelu(
    const short* __restrict__ X, const short* __restrict__ g,
    const short* __restrict__ be, short* __restrict__ out,
    const int* __restrict__ lens, const int domask)
{
  const int row = blockIdx.x, tid = threadIdx.x;
  const short* xr = X + (size_t)row * 1024;
  short4v xv = *(const short4v*)(xr + tid*4);
  float v[4];
#pragma unroll
  for (int k=0;k<4;++k) v[k] = b2f(xv[k]);
  float s  = v[0]+v[1]+v[2]+v[3];
  float sq = v[0]*v[0]+v[1]*v[1]+v[2]*v[2]+v[3]*v[3];
#pragma unroll
  for (int off=32; off>0; off>>=1){
    s  += __shfl_xor(s,  off, 64);
    sq += __shfl_xor(sq, off, 64);
  }
  __shared__ float red[8];
  if ((tid&63)==0){ red[tid>>6] = s; red[4+(tid>>6)] = sq; }
  __syncthreads();
  s  = red[0]+red[1]+red[2]+red[3];
  sq = red[4]+red[5]+red[6]+red[7];
  const float mean = s * (1.f/1024.f);
  const float var  = sq * (1.f/1024.f) - mean*mean;
  const float rstd = rsqrtf(var + 1e-5f);
  float zmul = 1.f;
  if (domask){ const int b = row >> 9, t = row & 511; if (t >= lens[b]) zmul = 0.f; }
  short4v o;
#pragma unroll
  for (int k=0;k<4;++k){
    const int n = tid*4 + k;
    float y = (v[k]-mean)*rstd*b2f(g[n]) + b2f(be[n]);
    y = (y >= 0.f) ? y : 0.01f*y;
    o[k] = f2b(y * zmul);
  }
  *(short4v*)(out + (size_t)row*1024 + tid*4) = o;
}

// ---------------------------------------------------------------------------
// Persistent bidirectional LSTM scan — R9 structure VERBATIM (frozen; best
// measured: 1717 us/dispatch). Tag-embedded h-state sync. Grid = 32*ndir WGs
// x 256 thr. WG dir = dir0 + (blk>>5); 16 units per WG. Wave w computes gate
// w (torch i,f,g,o); whh A-frags in VGPRs.
// h state global: [dir][buf(step parity)][32 batch][256 pair] u64,
//   hi 32 = tag (epoch<<10 | producing step+1), lo 32 = packed 2xbf16.
// Aligned 8B stores are single-copy atomic: consumers poll the DATA word
// (tag match == payload in hand; the successful spin attempt IS the
// transfer). Two barriers/step; hsh double-buffered; inductive no-clobber.
// ---------------------------------------------------------------------------
__global__ __launch_bounds__(256) void lstm_scan(
    const short* __restrict__ xp, const int xp_cols, const int dir0,
    const short* __restrict__ whh,      // layer base: [2][2048][512]
    u64* __restrict__ hstate,           // [2][2][32][256] tagged u64
    short* __restrict__ hout,           // [32][512][1024]
    const unsigned epoch)
{
  const int wg = blockIdx.x;
  const int dloc = wg >> 5, d = dir0 + dloc;
  const int u0 = (wg & 31) * 16;
  const int tid = threadIdx.x, lane = tid & 63, wv = tid >> 6;
  const int quad = lane >> 4, l15 = lane & 15;

  short8 af[16];
  {
    const short* wr = whh + ((size_t)d*2048 + wv*512 + u0 + l15)*512 + quad*8;
#pragma unroll
    for (int ks=0; ks<16; ++ks) af[ks] = *(const short8*)(wr + ks*32);
  }

  // gate-math ownership: thread = (batch bb, unit-pair pp)
  const int bb = tid >> 3, pp = tid & 7;
  float cstA = 0.f, cstB = 0.f;
  __shared__ __align__(16) unsigned hsh[2][32*260];  // double-buffered staging
  __shared__ float gl[4][16][33];
  const unsigned tbase = epoch << 10;

  for (int step=0; step<512; ++step){
    const int t = d ? (511-step) : step;
    // xp prefetch (overlaps the poll)
    short4v x0, x1;
    {
      const size_t gb = (size_t)dloc*2048 + (size_t)wv*512 + u0 + quad*4;
      x0 = *(const short4v*)(xp + ((size_t)l15*512      + t)*xp_cols + gb);
      x1 = *(const short4v*)(xp + ((size_t)(l15+16)*512 + t)*xp_cols + gb);
    }
    // stage: thread owns unit-pair `tid` of every batch k (lane-consecutive
    // global loads AND lane-consecutive LDS writes -> conflict-free)
    unsigned* stg = &hsh[step&1][tid];
    if (step == 0){
#pragma unroll
      for (int k=0;k<32;++k) stg[k*260] = 0u;        // h_0 = 0, no poll
    } else {
      const u64* hq = hstate + ((size_t)(d*2 + (step&1))<<13) + tid;
      const unsigned tgt = tbase + (unsigned)step;
      u64 v[32];
      for(;;){
        unsigned ok = 1u;
#pragma unroll
        for (int k=0;k<32;++k)
          v[k] = __hip_atomic_load(hq + (size_t)k*256,
                                   __ATOMIC_RELAXED, __HIP_MEMORY_SCOPE_AGENT);
#pragma unroll
        for (int k=0;k<32;++k) ok &= (unsigned)((unsigned)(v[k] >> 32) == tgt);
        if (ok) break;
        __builtin_amdgcn_s_sleep(1);
      }
#pragma unroll
      for (int k=0;k<32;++k) stg[k*260] = (unsigned)v[k];
    }
    __syncthreads();   // B1: staged h ready (also fences prev-step gl reads)

    float4v acc0, acc1;
#pragma unroll
    for (int g=0; g<4; ++g){ acc0[g] = b2f(x0[g]); acc1[g] = b2f(x1[g]); }
    const short* hs = (const short*)&hsh[step&1][0];
#pragma unroll
    for (int ks=0; ks<16; ++ks){
      short8 b0 = *(const short8*)(hs + (size_t)l15*520      + ks*32 + quad*8);
      short8 b1 = *(const short8*)(hs + (size_t)(l15+16)*520 + ks*32 + quad*8);
      acc0 = __builtin_amdgcn_mfma_f32_16x16x32_bf16(af[ks], b0, acc0, 0, 0, 0);
      acc1 = __builtin_amdgcn_mfma_f32_16x16x32_bf16(af[ks], b1, acc1, 0, 0, 0);
    }
#pragma unroll
    for (int g=0; g<4; ++g){
      gl[wv][quad*4+g][l15]    = acc0[g];   // gl[gate][unit 0..15][batch 0..31]
      gl[wv][quad*4+g][l15+16] = acc1[g];
    }
    __syncthreads();   // B2: gl ready (also fences prev-gen hsh buffer reads)

    float hv[2];
#pragma unroll
    for (int i=0; i<2; ++i){
      const int uu = 2*pp + i;
      const float gi = gl[0][uu][bb], gf = gl[1][uu][bb];
      const float gg = gl[2][uu][bb], go = gl[3][uu][bb];
      float& cref = i ? cstB : cstA;
      const float c = sigm(gf)*cref + sigm(gi)*tanh_(gg);
      cref = c;
      hv[i] = sigm(go) * tanh_(c);
    }
    const unsigned hw = (unsigned)(unsigned short)f2b(hv[0])
                      | ((unsigned)(unsigned short)f2b(hv[1]) << 16);
    const u64 pkt = ((u64)(tbase + (unsigned)step + 1u) << 32) | (u64)hw;
    __hip_atomic_store(hstate + ((size_t)(d*2 + ((step+1)&1))<<13)
                         + (size_t)bb*256 + (u0>>1) + pp,
                       pkt, __ATOMIC_RELAXED, __HIP_MEMORY_SCOPE_AGENT);
    *(unsigned*)&hout[((size_t)bb*512 + t)*1024 + d*512 + u0 + 2*pp] = hw;
    // no drain, no flag: the tagged store is self-announcing
  }
}

// ---------------------------------------------------------------------------
// Attention stage 1: per-step scores. Grid (8 t-chunks, 32 batches).
// scr[b][t] = h[b][t] . wu  (masked -inf for t >= len).
// ---------------------------------------------------------------------------
__global__ __launch_bounds__(256) void attn_scores(
    const short* __restrict__ hseq, const short* __restrict__ wu,
    float* __restrict__ scr, const int* __restrict__ lens)
{
  const int tc = blockIdx.x, b = blockIdx.y;
  const int tid = threadIdx.x, lane = tid & 63, wv = tid >> 6;
  const int len = lens[b];
  __shared__ float wus[1024];
  for (int i=tid; i<1024; i+=256) wus[i] = b2f(wu[i]);
  __syncthreads();
  const short* hb = hseq + (size_t)b*512*1024;
  for (int tt=wv; tt<64; tt+=4){
    const int t = tc*64 + tt;
    const short* hr = hb + (size_t)t*1024;
    float s = 0.f;
#pragma unroll
    for (int j=0;j<16;++j) s += b2f(hr[lane + j*64]) * wus[lane + j*64];
#pragma unroll
    for (int off=32; off>0; off>>=1) s += __shfl_xor(s, off, 64);
    if (lane==0) scr[(size_t)b*512 + t] = (t < len) ? s : -3.0e38f;
  }
}

// ---------------------------------------------------------------------------
// Attention stage 2: masked softmax over 512 scores, in-place -> alpha.
// Grid 32. lens >= 256 always, so the max over the first 256 is real data.
// ---------------------------------------------------------------------------
__global__ __launch_bounds__(256) void attn_softmax(
    float* __restrict__ scr, const int* __restrict__ lens)
{
  const int b = blockIdx.x, tid = threadIdx.x, lane = tid & 63, wv = tid >> 6;
  const int len = lens[b];
  float* sb = scr + (size_t)b*512;
  const float v0 = sb[tid], v1 = sb[tid+256];
  __shared__ float red[8];
  float m = fmaxf(v0, v1);
#pragma unroll
  for (int off=32; off>0; off>>=1) m = fmaxf(m, __shfl_xor(m, off, 64));
  if (lane==0) red[wv] = m;
  __syncthreads();
  m = fmaxf(fmaxf(red[0],red[1]), fmaxf(red[2],red[3]));
  const float e0 = (tid     < len) ? __expf(v0 - m) : 0.f;
  const float e1 = (tid+256 < len) ? __expf(v1 - m) : 0.f;
  float s = e0 + e1;
#pragma unroll
  for (int off=32; off>0; off>>=1) s += __shfl_xor(s, off, 64);
  if (lane==0) red[4+wv] = s;
  __syncthreads();
  s = red[4]+red[5]+red[6]+red[7];
  const float inv = 1.f/s;
  sb[tid]     = e0*inv;
  sb[tid+256] = e1*inv;
}

// ---------------------------------------------------------------------------
// Attention stage 3: pooled[b][f] = sum_t alpha[b][t] * h[b][t][f].
// Grid (8 feature-chunks of 128, 32 batches). Thread owns 4 features and a
// 64-step t-strip; strips reduced via LDS. alpha=0 beyond len -> exact.
// ---------------------------------------------------------------------------
__global__ __launch_bounds__(256) void attn_pool(
    const short* __restrict__ hseq, const float* __restrict__ scr,
    float* __restrict__ pooled)
{
  const int fc = blockIdx.x, b = blockIdx.y;
  const int tid = threadIdx.x;
  const int strip = tid >> 5, l32v = tid & 31;
  __shared__ float al[512];
  __shared__ float red[8][132];
  for (int i=tid; i<512; i+=256) al[i] = scr[(size_t)b*512 + i];
  __syncthreads();
  const short* hbase = hseq + (size_t)b*512*1024 + fc*128 + l32v*4;
  float4v acc = (float4v)0.f;
  for (int tt=0; tt<64; ++tt){
    const int t = strip*64 + tt;
    const float a = al[t];
    short4v hv = *(const short4v*)(hbase + (size_t)t*1024);
    acc[0] += a*b2f(hv[0]); acc[1] += a*b2f(hv[1]);
    acc[2] += a*b2f(hv[2]); acc[3] += a*b2f(hv[3]);
  }
#pragma unroll
  for (int k=0;k<4;++k) red[strip][l32v*4+k] = acc[k];
  __syncthreads();
  if (tid < 128){
    float s = 0.f;
#pragma unroll
    for (int st=0; st<8; ++st) s += red[st][tid];
    pooled[(size_t)b*1024 + fc*128 + tid] = s;
  }
}

// ---------------------------------------------------------------------------
// Attention stage 4: classifier. Grid 32. out[b][j] = Wc[j].pooled[b] + bc[j].
// ---------------------------------------------------------------------------
__global__ __launch_bounds__(256) void attn_cls2(
    const float* __restrict__ pooled, const short* __restrict__ Wc,
    const short* __restrict__ bc, float* __restrict__ out)
{
  const int b = blockIdx.x, tid = threadIdx.x;
  const int j = tid >> 5, l32 = tid & 31;
  const float* pb = pooled + (size_t)b*1024;
  float s2 = 0.f;
  for (int kk=l32; kk<1024; kk+=32) s2 += b2f(Wc[j*1024+kk]) * pb[kk];
#pragma unroll
  for (int off=16; off>0; off>>=1) s2 += __shfl_xor(s2, off, 32);
  if (l32==0) out[b*8+j] = s2 + b2f(bc[j]);
}

// ---------------------------------------------------------------------------
extern "C" void kernel_launch(void* const* d_in, const int* in_sizes, int n_in,
                              void* d_out, int out_size, void* d_ws, size_t ws_size,
                              hipStream_t stream)
{
  (void)in_sizes; (void)n_in; (void)out_size;
  const int*   lens = (const int*)d_in[1];
  float* outp = (float*)d_out;

  const size_t SZ_XP_A = (size_t)16384*4096*2;   // 134,217,728 B
  const size_t SZ_XP_B = (size_t)16384*2048*2;   //  67,108,864 B
  const size_t SZ_H    = (size_t)16384*1024*2;   //  33,554,432 B
  const size_t SZ_HS   = 262144;                 // 4 bufs x 8192 tagged u64
  const size_t SZ_CNT  = 16384;
  const size_t SZ_NORM = 37000000;               // bf16 copies of all inputs
  const bool planA = ws_size >= SZ_XP_A + 2*SZ_H + SZ_HS + SZ_CNT + SZ_NORM;
  const bool planB = !planA && ws_size >= SZ_XP_B + 2*SZ_H + SZ_HS + SZ_CNT + SZ_NORM;
  if (!planA && !planB) return;  // clean failure beats a core dump
  const size_t xpsz = planA ? SZ_XP_A : SZ_XP_B;

  char* ws = (char*)d_ws;
  short*    XP  = (short*)ws;
  short*    HB  = (short*)(ws + xpsz);
  short*    HC  = (short*)(ws + xpsz + SZ_H);
  u64*      HS64= (u64*)(ws + xpsz + 2*SZ_H);
  unsigned* CNT = (unsigned*)(ws + xpsz + 2*SZ_H + SZ_HS);
  unsigned* FLAG = CNT + 4000;
  short*    pool = (short*)(ws + xpsz + 2*SZ_H + SZ_HS + SZ_CNT);

  // carve bf16 copies (128-element aligned)
  size_t off = 0;
  auto carve = [&](size_t n){ short* p = pool + off; off += (n + 127) & ~(size_t)127; return p; };
  short* x   = carve(4194304);
  short* W1  = carve(262144);
  short* b1  = carve(1024);
  short* g1  = carve(1024);
  short* be1 = carve(1024);
  short* W2  = carve(1048576);
  short* b2  = carve(1024);
  short* g2  = carve(1024);
  short* be2 = carve(1024);
  short* wih = carve(8388608);
  short* whh = carve(4194304);
  short* bih = carve(8192);
  short* bhh = carve(8192);
  short* wu  = carve(1024);
  short* Wc  = carve(8192);
  short* bc  = carve(8);

  // zero the tagged h-state once: no garbage tag can match epoch>=1 targets.
  hipMemsetAsync(HS64, 0, SZ_HS, stream);
  detect_f32<<<1, 256, 0, stream>>>((const unsigned short*)d_in[0], FLAG);

  // single batched convert launch for all 16 tensors
  {
    struct { int idx; short* dst; int n; } cv[16] = {
      {0,x,4194304},{2,W1,262144},{3,b1,1024},{4,g1,1024},{5,be1,1024},
      {6,W2,1048576},{7,b2,1024},{8,g2,1024},{9,be2,1024},
      {10,wih,8388608},{11,whh,4194304},{12,bih,8192},{13,bhh,8192},
      {14,wu,1024},{16,Wc,8192},{17,bc,8}
    };
    CvtArgs a;
    int acc = 0;
    for (int i=0;i<16;++i){
      a.src[i]  = d_in[cv[i].idx];
      a.dst[i]  = cv[i].dst;
      a.n[i]    = cv[i].n;
      a.boff[i] = acc;
      acc += (cv[i].n + 255) / 256;
    }
    a.boff[16] = acc;
    to_bf16_batch<<<acc, 256, 0, stream>>>(a, FLAG);
  }

  dim3 blk(256);
  // extract MLP
  gemm_bt<<<dim3(8,128),  blk, 0, stream>>>(x,  W1, XP, b1, nullptr, 1024, 256);
  ln_lrelu<<<16384, blk, 0, stream>>>(XP, g1, be1, HB, lens, 0);
  gemm_bt<<<dim3(8,128),  blk, 0, stream>>>(HB, W2, XP, b2, nullptr, 1024, 1024);
  ln_lrelu<<<16384, blk, 0, stream>>>(XP, g2, be2, HC, lens, 1);   // + pad mask

  const short* lin[2]  = { HC, HB };   // layer inputs
  short*       lout[2] = { HB, HC };   // layer outputs
  for (int l = 0; l < 2; ++l){
    const short* whh_l = whh + (size_t)l*2*2048*512;
    if (planA){
      gemm_bt<<<dim3(32,128), blk, 0, stream>>>(
          lin[l], wih + (size_t)l*4096*1024, XP,
          bih + l*4096, bhh + l*4096, 4096, 1024);
      lstm_scan<<<64, blk, 0, stream>>>(XP, 4096, 0, whh_l, HS64, lout[l],
                                        (unsigned)(l+1));
    } else {
      for (int d = 0; d < 2; ++d){
        gemm_bt<<<dim3(16,128), blk, 0, stream>>>(
            lin[l], wih + ((size_t)(l*2+d))*2048*1024, XP,
            bih + (l*2+d)*2048, bhh + (l*2+d)*2048, 2048, 1024);
        lstm_scan<<<32, blk, 0, stream>>>(XP, 2048, d, whh_l, HS64, lout[l],
                                          (unsigned)(l+1));
      }
    }
  }
  // attention + classifier (4-stage, parallelized; scratch in dead XP)
  float* SCR  = (float*)XP;            // [32][512] scores -> alpha
  float* POOL = SCR + 32*512;          // [32][1024] pooled
  attn_scores<<<dim3(8,32), blk, 0, stream>>>(HC, wu, SCR, lens);
  attn_softmax<<<32, blk, 0, stream>>>(SCR, lens);
  attn_pool<<<dim3(8,32), blk, 0, stream>>>(HC, SCR, POOL);
  attn_cls2<<<32, blk, 0, stream>>>(POOL, Wc, bc, outp);
}